// Round 3
// baseline (282.478 us; speedup 1.0000x reference)
//
#include <hip/hip_runtime.h>
#include <hip/hip_bf16.h>

// ---------------------------------------------------------------------------
// 2-layer GAT (PyG GATConv semantics, eval mode, self-loops appended).
//   1) bucket (dst>>9, LDS-staged bucket-ordered writes -> coalesced runs)
//      -> csr_bucket (512-node buckets, 1024 thr + int4 sweeps, R1)
//   2) gemm1 (MFMA 16x16x32 bf16): h1 = x @ W1 -> bf16 + a_s/a_d epilogue
//   3) agg1: additive exp(v-8) agg, 16 lanes/edge ushort4 (R11 verified 59.8us)
//   4) gemm2: he @ W2 -> bf16 + a_s2/a_d2 epilogue (separate kernel)
//   5) agg2: additive agg, 4 lanes/edge ushort4 + fused log_softmax
// Lessons encoded:
//   R8  - never co-schedule scatter/atomic and MFMA personalities in one grid.
//   R10 - keep per-lane gather staging <= 8 B (ushort4), else the
//         occupancy-targeted VGPR budget serializes the gathers.
//   R12 - do NOT fuse gemm2 into agg1: any epilogue fattening (VGPR 24->28)
//         makes the allocator restructure the gather loop (3x confirmed).
//   R14 - bucket writes staged through LDS so each bucket's entries leave the
//         block as one contiguous run instead of 4 B random scatters.
//   R1(this session) - csr_bucket widened to 1024 thr + int4 loads (-8us).
//   R2(this session) - bucket_kernel was 391 blocks (1.5/CU, latency-bound
//         dependent LDS-atomic chains); ECHUNK 4096->2048 -> 782 blocks.
// ---------------------------------------------------------------------------

#define NEG_SLOPE 0.2f
#define EPS_DEN 1e-16f
#define CSHIFT 8.0f          // shift-invariant softmax; |logit| <~ 9 here
#define NBUCK_MAX 256
#define BCAP 16384
#define ECHUNK 2048          // edges per bucket block (8 per thread, R2)
#define G1_PITCH 136

typedef __attribute__((ext_vector_type(8))) short bf16x8;
typedef __attribute__((ext_vector_type(4))) float f32x4;

__device__ __forceinline__ float bf2f(unsigned short u) {
    return __uint_as_float(((unsigned)u) << 16);
}
__device__ __forceinline__ unsigned short f2bf(float f) {
    unsigned x = __float_as_uint(f);
    unsigned r = x + 0x7fffu + ((x >> 16) & 1u);
    return (unsigned short)(r >> 16);
}

// ---------------- CSR build ----------------

// bucket by dst>>9; entries staged bucket-ordered in LDS, copied out in
// per-bucket contiguous runs (~10 entries = 40 B) for write coalescing.
__global__ __launch_bounds__(256) void bucket_kernel(
    const int* __restrict__ src, const int* __restrict__ dst,
    int* __restrict__ gcur, int* __restrict__ buf, int E, int nbuck)
{
    __shared__ int cnt[NBUCK_MAX];       // counts -> placement cursors
    __shared__ int loff[NBUCK_MAX];      // local exclusive offsets
    __shared__ int offs[NBUCK_MAX];      // global segment base per bucket
    __shared__ int wsum[4];
    __shared__ int ldata[ECHUNK];        // packed entries, bucket-ordered
    __shared__ unsigned char bid[ECHUNK];// bucket id per slot (nbuck <= 256)
    int tid = threadIdx.x, lane = tid & 63, wv = tid >> 6;
    for (int i = tid; i < nbuck; i += 256) cnt[i] = 0;
    __syncthreads();
    int base = blockIdx.x * ECHUNK;
    int lim = min(base + ECHUNK, E);
    int dl[8];                           // ECHUNK == 256*8
#pragma unroll
    for (int k = 0; k < 8; ++k) {
        int e = base + tid + 256 * k;
        dl[k] = (e < lim) ? dst[e] : -1;
    }
#pragma unroll
    for (int k = 0; k < 8; ++k)
        if (dl[k] >= 0) atomicAdd(&cnt[dl[k] >> 9], 1);
    __syncthreads();
    // 256-wide exclusive scan of counts (thread t <-> bucket t)
    int c = (tid < nbuck) ? cnt[tid] : 0;
    int sc = c;
#pragma unroll
    for (int off = 1; off < 64; off <<= 1) {
        int o = __shfl_up(sc, off);
        if (lane >= off) sc += o;
    }
    if (lane == 63) wsum[wv] = sc;
    __syncthreads();
    if (tid == 0) {
        int acc = 0;
#pragma unroll
        for (int k = 0; k < 4; ++k) { int t = wsum[k]; wsum[k] = acc; acc += t; }
    }
    __syncthreads();
    if (tid < nbuck) {
        loff[tid] = wsum[wv] + sc - c;
        offs[tid] = atomicAdd(&gcur[tid], c);
        cnt[tid] = 0;                    // reuse as placement cursor
    }
    __syncthreads();
    // place entries bucket-ordered in LDS
#pragma unroll
    for (int k = 0; k < 8; ++k) {
        if (dl[k] >= 0) {
            int e = base + tid + 256 * k;
            int b = dl[k] >> 9;
            int slot = loff[b] + atomicAdd(&cnt[b], 1);
            ldata[slot] = (src[e] << 9) | (dl[k] & 511);
            bid[slot] = (unsigned char)b;
        }
    }
    __syncthreads();
    // copy out: consecutive slots in a bucket -> consecutive global dests
    int total = lim - base;
    for (int i = tid; i < total; i += 256) {
        int b = bid[i];
        int o = offs[b] + (i - loff[b]);
        if (o < BCAP) buf[(size_t)b * BCAP + o] = ldata[i];
    }
}

// per-512-node-bucket hist + scan + place.
// R1: 1024 threads (16 waves) + int4 sweeps — the 256-thr version was
// latency-bound at 196 blocks (<1 block/CU, 32 serial sweep iterations).
__global__ __launch_bounds__(1024) void csr_bucket_kernel(
    const int* __restrict__ gcur, const int* __restrict__ buf,
    int* __restrict__ rowptr, int* __restrict__ srcs, int N, int E)
{
    __shared__ int cnt[512];
    __shared__ int wsum[16];
    __shared__ int wbase[8];
    __shared__ int basesh;
    int b = blockIdx.x, tid = threadIdx.x;
    int lane = tid & 63, wv = tid >> 6;      // wv in 0..15
    if (tid < 512) cnt[tid] = 0;
    // inline prefix: base = sum_{i<b} gcur[i]  (<=196 L2-hot ints, 1 sweep)
    int part = 0;
    for (int i = tid; i < b; i += 1024) part += gcur[i];
#pragma unroll
    for (int off = 32; off >= 1; off >>= 1) part += __shfl_xor(part, off);
    if (lane == 0) wsum[wv] = part;
    __syncthreads();
    if (tid == 0) {
        int acc = 0;
#pragma unroll
        for (int k = 0; k < 16; ++k) acc += wsum[k];
        basesh = acc;
    }
    __syncthreads();
    int n = min(gcur[b], BCAP);
    const int* p = buf + (size_t)b * BCAP;
    const int4* p4 = (const int4*)p;         // 64 KiB-aligned segment
    int n4 = n >> 2;
    // phase 1: histogram (int4-vectorized, ~2 sweeps at 1024 thr)
    for (int i = tid; i < n4; i += 1024) {
        int4 v = p4[i];
        atomicAdd(&cnt[v.x & 511], 1);
        atomicAdd(&cnt[v.y & 511], 1);
        atomicAdd(&cnt[v.z & 511], 1);
        atomicAdd(&cnt[v.w & 511], 1);
    }
    for (int i = (n4 << 2) + tid; i < n; i += 1024)
        atomicAdd(&cnt[p[i] & 511], 1);
    __syncthreads();
    // scan of 512 counters on the first 8 waves (thread t <-> counter t)
    int c = (tid < 512) ? cnt[tid] : 0;
    int sc = c;
#pragma unroll
    for (int off = 1; off < 64; off <<= 1) {
        int o = __shfl_up(sc, off);
        if (lane >= off) sc += o;
    }
    if (lane == 63 && wv < 8) wsum[wv] = sc;
    __syncthreads();
    if (tid == 0) {
        int acc = 0;
#pragma unroll
        for (int k = 0; k < 8; ++k) { wbase[k] = acc; acc += wsum[k]; }
    }
    __syncthreads();
    if (tid < 512) {
        int g0 = basesh + wbase[wv] + (sc - c);   // exclusive prefix
        int node0 = (b << 9) + tid;
        if (node0 < N) rowptr[node0] = g0;
        cnt[tid] = g0;                            // placement cursor
    }
    __syncthreads();
    // phase 2: place (int4-vectorized)
    for (int i = tid; i < n4; i += 1024) {
        int4 v = p4[i];
        int px = atomicAdd(&cnt[v.x & 511], 1); srcs[px] = v.x >> 9;
        int py = atomicAdd(&cnt[v.y & 511], 1); srcs[py] = v.y >> 9;
        int pz = atomicAdd(&cnt[v.z & 511], 1); srcs[pz] = v.z >> 9;
        int pw = atomicAdd(&cnt[v.w & 511], 1); srcs[pw] = v.w >> 9;
    }
    for (int i = (n4 << 2) + tid; i < n; i += 1024) {
        int v = p[i];
        int posi = atomicAdd(&cnt[v & 511], 1);
        srcs[posi] = v >> 9;
    }
    if (b == 0 && tid == 0) rowptr[N] = E;
}

// ---------------- GEMM1 (MFMA): [N,128] @ [128,64] -> bf16 -------------------

__global__ __launch_bounds__(256) void gemm1_mfma_kernel(
    const float* __restrict__ x, const float* __restrict__ W1,
    const float* __restrict__ att_s, const float* __restrict__ att_d,
    unsigned short* __restrict__ h1b, float* __restrict__ a_s,
    float* __restrict__ a_d, int N)
{
    __shared__ unsigned short As[64 * G1_PITCH];
    __shared__ unsigned short Cs[64 * 68];
    int tid = threadIdx.x;
    int lane = tid & 63, wv = tid >> 6;
    int quad = lane >> 4, l16 = lane & 15;

    bf16x8 Bf[4][4];
#pragma unroll
    for (int ks = 0; ks < 4; ++ks)
#pragma unroll
        for (int nt = 0; nt < 4; ++nt) {
            bf16x8 f;
#pragma unroll
            for (int j = 0; j < 8; ++j)
                f[j] = (short)f2bf(W1[(ks * 32 + quad * 8 + j) * 64 + nt * 16 + l16]);
            Bf[ks][nt] = f;
        }
    float asw[4], adw[4];
#pragma unroll
    for (int nt = 0; nt < 4; ++nt) {
        asw[nt] = att_s[nt * 16 + l16];
        adw[nt] = att_d[nt * 16 + l16];
    }

    int nblocks = (N + 63) >> 6;
    for (int blk = blockIdx.x; blk < nblocks; blk += gridDim.x) {
        int row0 = blk << 6;
        __syncthreads();
#pragma unroll
        for (int i = 0; i < 8; ++i) {
            int idx = tid + 256 * i;
            int r = idx >> 5, c4 = idx & 31;
            int row = row0 + r;
            float4 v = (row < N) ? ((const float4*)x)[(size_t)row * 32 + c4]
                                 : make_float4(0.f, 0.f, 0.f, 0.f);
            ushort4 u;
            u.x = f2bf(v.x); u.y = f2bf(v.y); u.z = f2bf(v.z); u.w = f2bf(v.w);
            *(ushort4*)&As[r * G1_PITCH + c4 * 4] = u;
        }
        __syncthreads();
        f32x4 acc[4];
#pragma unroll
        for (int nt = 0; nt < 4; ++nt) acc[nt] = (f32x4){0.f, 0.f, 0.f, 0.f};
#pragma unroll
        for (int ks = 0; ks < 4; ++ks) {
            bf16x8 Af = *(const bf16x8*)&As[(wv * 16 + l16) * G1_PITCH + ks * 32 + quad * 8];
#pragma unroll
            for (int nt = 0; nt < 4; ++nt)
                acc[nt] = __builtin_amdgcn_mfma_f32_16x16x32_bf16(Af, Bf[ks][nt], acc[nt], 0, 0, 0);
        }
        int lrow = wv * 16 + quad * 4;
#pragma unroll
        for (int nt = 0; nt < 4; ++nt) {
            float ps[4], pd[4];
#pragma unroll
            for (int r = 0; r < 4; ++r) {
                ps[r] = acc[nt][r] * asw[nt];
                pd[r] = acc[nt][r] * adw[nt];
            }
#pragma unroll
            for (int off = 1; off < 8; off <<= 1)
#pragma unroll
                for (int r = 0; r < 4; ++r) {
                    ps[r] += __shfl_xor(ps[r], off);
                    pd[r] += __shfl_xor(pd[r], off);
                }
            if ((l16 & 7) == 0) {
                int head = nt * 2 + (l16 >> 3);
#pragma unroll
                for (int r = 0; r < 4; ++r) {
                    int row = row0 + lrow + r;
                    if (row < N) {
                        a_s[row * 8 + head] = ps[r];
                        a_d[row * 8 + head] = pd[r];
                    }
                }
            }
        }
#pragma unroll
        for (int nt = 0; nt < 4; ++nt)
#pragma unroll
            for (int r = 0; r < 4; ++r)
                Cs[(lrow + r) * 68 + nt * 16 + l16] = f2bf(acc[nt][r]);
        __syncthreads();
#pragma unroll
        for (int i = 0; i < 4; ++i) {
            int idx = tid + 256 * i;
            int r = idx >> 4, c4 = idx & 15;
            int row = row0 + r;
            if (row < N) {
                ushort4 u = *(const ushort4*)&Cs[r * 68 + c4 * 4];
                ((ushort4*)h1b)[(size_t)row * 16 + c4] = u;
            }
        }
    }
}

// ---------------- agg1: additive exp(v-8) agg, 16 edges in flight ------------
// q=lane>>4 edge-group (stride 4), pos=lane&15 -> channels 4pos..4pos+3,
// head hp=pos>>1. R11-verified 59.8us shape — do not fatten this kernel.

__global__ __launch_bounds__(256) void agg1_kernel(
    const unsigned short* __restrict__ h1b, const float* __restrict__ a_s,
    const float* __restrict__ a_d, const int* __restrict__ rowptr,
    const int* __restrict__ srcs, const float* __restrict__ b1,
    unsigned short* __restrict__ heb, int N)
{
    int lane = threadIdx.x & 63, wid = threadIdx.x >> 6;
    int node = blockIdx.x * 4 + wid;
    if (node >= N) return;
    int q = lane >> 4, pos = lane & 15, hp = pos >> 1;
    int beg = rowptr[node], end = rowptr[node + 1];
    float adn = a_d[node * 8 + hp];
    const ushort4* h1v = (const ushort4*)h1b;    // row stride 16 ushort4

    float l = 0.f, a0 = 0.f, a1 = 0.f, a2 = 0.f, a3 = 0.f;
    if (q == 0) {                                // self-loop in group 0
        float v = a_s[node * 8 + hp] + adn;
        v = fmaxf(v, NEG_SLOPE * v);
        float p = __expf(v - CSHIFT);
        ushort4 h = h1v[(size_t)node * 16 + pos];
        l = p;
        a0 = p * bf2f(h.x); a1 = p * bf2f(h.y);
        a2 = p * bf2f(h.z); a3 = p * bf2f(h.w);
    }
    int e = beg + q;
    for (; e + 12 < end; e += 16) {
        int s0 = srcs[e], s1 = srcs[e + 4], s2 = srcs[e + 8], s3 = srcs[e + 12];
        float va0 = a_s[s0 * 8 + hp], va1 = a_s[s1 * 8 + hp];
        float va2 = a_s[s2 * 8 + hp], va3 = a_s[s3 * 8 + hp];
        ushort4 h0 = h1v[(size_t)s0 * 16 + pos];
        ushort4 h1_ = h1v[(size_t)s1 * 16 + pos];
        ushort4 h2_ = h1v[(size_t)s2 * 16 + pos];
        ushort4 h3_ = h1v[(size_t)s3 * 16 + pos];
        float v0 = va0 + adn; v0 = fmaxf(v0, NEG_SLOPE * v0);
        float v1 = va1 + adn; v1 = fmaxf(v1, NEG_SLOPE * v1);
        float v2 = va2 + adn; v2 = fmaxf(v2, NEG_SLOPE * v2);
        float v3 = va3 + adn; v3 = fmaxf(v3, NEG_SLOPE * v3);
        float p0 = __expf(v0 - CSHIFT), p1 = __expf(v1 - CSHIFT);
        float p2 = __expf(v2 - CSHIFT), p3 = __expf(v3 - CSHIFT);
        l += p0 + p1 + p2 + p3;
        a0 = fmaf(p0, bf2f(h0.x), a0); a1 = fmaf(p0, bf2f(h0.y), a1);
        a2 = fmaf(p0, bf2f(h0.z), a2); a3 = fmaf(p0, bf2f(h0.w), a3);
        a0 = fmaf(p1, bf2f(h1_.x), a0); a1 = fmaf(p1, bf2f(h1_.y), a1);
        a2 = fmaf(p1, bf2f(h1_.z), a2); a3 = fmaf(p1, bf2f(h1_.w), a3);
        a0 = fmaf(p2, bf2f(h2_.x), a0); a1 = fmaf(p2, bf2f(h2_.y), a1);
        a2 = fmaf(p2, bf2f(h2_.z), a2); a3 = fmaf(p2, bf2f(h2_.w), a3);
        a0 = fmaf(p3, bf2f(h3_.x), a0); a1 = fmaf(p3, bf2f(h3_.y), a1);
        a2 = fmaf(p3, bf2f(h3_.z), a2); a3 = fmaf(p3, bf2f(h3_.w), a3);
    }
    for (; e < end; e += 4) {
        int s = srcs[e];
        float va = a_s[s * 8 + hp];
        ushort4 h = h1v[(size_t)s * 16 + pos];
        float v = va + adn; v = fmaxf(v, NEG_SLOPE * v);
        float p = __expf(v - CSHIFT);
        l += p;
        a0 = fmaf(p, bf2f(h.x), a0); a1 = fmaf(p, bf2f(h.y), a1);
        a2 = fmaf(p, bf2f(h.z), a2); a3 = fmaf(p, bf2f(h.w), a3);
    }
#pragma unroll
    for (int off = 16; off < 64; off <<= 1) {
        l  += __shfl_xor(l, off);
        a0 += __shfl_xor(a0, off); a1 += __shfl_xor(a1, off);
        a2 += __shfl_xor(a2, off); a3 += __shfl_xor(a3, off);
    }
    if (q == 0) {
        float inv = 1.f / (l + EPS_DEN);
        float4 bb = ((const float4*)b1)[pos];
        float o0 = fmaf(a0, inv, bb.x);
        float o1 = fmaf(a1, inv, bb.y);
        float o2 = fmaf(a2, inv, bb.z);
        float o3 = fmaf(a3, inv, bb.w);
        o0 = o0 > 0.f ? o0 : __expf(o0) - 1.f;   // ELU
        o1 = o1 > 0.f ? o1 : __expf(o1) - 1.f;
        o2 = o2 > 0.f ? o2 : __expf(o2) - 1.f;
        o3 = o3 > 0.f ? o3 : __expf(o3) - 1.f;
        ushort4 u;
        u.x = f2bf(o0); u.y = f2bf(o1); u.z = f2bf(o2); u.w = f2bf(o3);
        ((ushort4*)heb)[(size_t)node * 16 + pos] = u;
    }
}

// ---------------- GEMM2: [N,64] @ [64,16] -> bf16 + a_s2/a_d2 epilogue -------

__global__ __launch_bounds__(256) void gemm2_kernel(
    const unsigned short* __restrict__ heb, const float* __restrict__ W2,
    const float* __restrict__ att_s2, const float* __restrict__ att_d2,
    unsigned short* __restrict__ h2b, float* __restrict__ a_s2,
    float* __restrict__ a_d2, int N)
{
    __shared__ float xs[4][4 * 68];
    int lane = threadIdx.x & 63, wid = threadIdx.x >> 6;
    int sub = lane >> 4, c = lane & 15;
    float wcol[64];
#pragma unroll
    for (int k = 0; k < 64; ++k) wcol[k] = W2[k * 16 + c];
    float asw = att_s2[c], adw = att_d2[c];
    int groups = (N + 15) >> 4;
    int iters = (groups + gridDim.x - 1) / gridDim.x;
    for (int it = 0; it < iters; ++it) {
        int g = blockIdx.x + it * gridDim.x;
        int nb = g * 16 + wid * 4;
        __syncthreads();
        if (g < groups) {
#pragma unroll
            for (int i = 0; i < 4; ++i) {
                int n = nb + i;
                xs[wid][i * 68 + lane] = (n < N) ? bf2f(heb[(size_t)n * 64 + lane]) : 0.f;
            }
        }
        __syncthreads();
        if (g < groups) {
            int node = nb + sub;
            const float4* xv = (const float4*)&xs[wid][sub * 68];
            float acc = 0.f;
#pragma unroll
            for (int k4 = 0; k4 < 16; ++k4) {
                float4 v = xv[k4];
                acc += v.x * wcol[4 * k4 + 0] + v.y * wcol[4 * k4 + 1]
                     + v.z * wcol[4 * k4 + 2] + v.w * wcol[4 * k4 + 3];
            }
            if (node < N) {
                h2b[(size_t)node * 16 + c] = f2bf(acc);
                float rs = acc * asw, rd = acc * adw;
#pragma unroll
                for (int off = 1; off < 16; off <<= 1) {
                    rs += __shfl_xor(rs, off);
                    rd += __shfl_xor(rd, off);
                }
                if (c == 0) { a_s2[node] = rs; a_d2[node] = rd; }
            }
        }
    }
}

// ---------------- agg2: additive exp(v-8) agg + fused log_softmax ------------
// q=lane>>2 edge-group (stride 16), pos=lane&3 -> classes 4pos..4pos+3.

__global__ __launch_bounds__(256) void agg2_kernel(
    const unsigned short* __restrict__ h2b, const float* __restrict__ a_s2,
    const float* __restrict__ a_d2, const int* __restrict__ rowptr,
    const int* __restrict__ srcs, const float* __restrict__ b2,
    float* __restrict__ out, int N)
{
    int lane = threadIdx.x & 63, wid = threadIdx.x >> 6;
    int node = blockIdx.x * 4 + wid;
    if (node >= N) return;
    int q = lane >> 2, pos = lane & 3;
    int beg = rowptr[node], end = rowptr[node + 1];
    float adn = a_d2[node];
    const ushort4* h2v = (const ushort4*)h2b;    // row stride 4 ushort4

    float l = 0.f, a0 = 0.f, a1 = 0.f, a2 = 0.f, a3 = 0.f;
    if (q == 0) {                                // self-loop in group 0
        float v = a_s2[node] + adn;
        v = fmaxf(v, NEG_SLOPE * v);
        float p = __expf(v - CSHIFT);
        ushort4 h = h2v[(size_t)node * 4 + pos];
        l = p;
        a0 = p * bf2f(h.x); a1 = p * bf2f(h.y);
        a2 = p * bf2f(h.z); a3 = p * bf2f(h.w);
    }
    int e = beg + q;
    for (; e + 16 < end; e += 32) {
        int s0 = srcs[e], s1 = srcs[e + 16];
        float va0 = a_s2[s0], va1 = a_s2[s1];
        ushort4 h0 = h2v[(size_t)s0 * 4 + pos];
        ushort4 h1_ = h2v[(size_t)s1 * 4 + pos];
        float v0 = va0 + adn; v0 = fmaxf(v0, NEG_SLOPE * v0);
        float v1 = va1 + adn; v1 = fmaxf(v1, NEG_SLOPE * v1);
        float p0 = __expf(v0 - CSHIFT), p1 = __expf(v1 - CSHIFT);
        l += p0 + p1;
        a0 = fmaf(p0, bf2f(h0.x), a0); a1 = fmaf(p0, bf2f(h0.y), a1);
        a2 = fmaf(p0, bf2f(h0.z), a2); a3 = fmaf(p0, bf2f(h0.w), a3);
        a0 = fmaf(p1, bf2f(h1_.x), a0); a1 = fmaf(p1, bf2f(h1_.y), a1);
        a2 = fmaf(p1, bf2f(h1_.z), a2); a3 = fmaf(p1, bf2f(h1_.w), a3);
    }
    for (; e < end; e += 16) {
        int s = srcs[e];
        float va = a_s2[s];
        ushort4 h = h2v[(size_t)s * 4 + pos];
        float v = va + adn; v = fmaxf(v, NEG_SLOPE * v);
        float p = __expf(v - CSHIFT);
        l += p;
        a0 = fmaf(p, bf2f(h.x), a0); a1 = fmaf(p, bf2f(h.y), a1);
        a2 = fmaf(p, bf2f(h.z), a2); a3 = fmaf(p, bf2f(h.w), a3);
    }
#pragma unroll
    for (int off = 4; off < 64; off <<= 1) {
        l  += __shfl_xor(l, off);
        a0 += __shfl_xor(a0, off); a1 += __shfl_xor(a1, off);
        a2 += __shfl_xor(a2, off); a3 += __shfl_xor(a3, off);
    }
    if (q == 0) {
        float inv = 1.f / (l + EPS_DEN);
        float4 bb = ((const float4*)b2)[pos];
        float o0 = fmaf(a0, inv, bb.x);
        float o1 = fmaf(a1, inv, bb.y);
        float o2 = fmaf(a2, inv, bb.z);
        float o3 = fmaf(a3, inv, bb.w);
        float mx = fmaxf(fmaxf(o0, o1), fmaxf(o2, o3));
        mx = fmaxf(mx, __shfl_xor(mx, 1));
        mx = fmaxf(mx, __shfl_xor(mx, 2));
        float se = __expf(o0 - mx) + __expf(o1 - mx)
                 + __expf(o2 - mx) + __expf(o3 - mx);
        se += __shfl_xor(se, 1);
        se += __shfl_xor(se, 2);
        float ls = mx + logf(se);
        ((float4*)out)[(size_t)node * 4 + pos] =
            make_float4(o0 - ls, o1 - ls, o2 - ls, o3 - ls);
    }
}

// ---------------------------------------------------------------------------

extern "C" void kernel_launch(void* const* d_in, const int* in_sizes, int n_in,
                              void* d_out, int out_size, void* d_ws, size_t ws_size,
                              hipStream_t stream) {
    const float* x    = (const float*)d_in[0];
    const int*   ei   = (const int*)d_in[1];
    const float* W1   = (const float*)d_in[2];
    const float* b1   = (const float*)d_in[3];
    const float* as1  = (const float*)d_in[4];
    const float* ad1  = (const float*)d_in[5];
    const float* W2   = (const float*)d_in[6];
    const float* b2   = (const float*)d_in[7];
    const float* as2  = (const float*)d_in[8];
    const float* ad2  = (const float*)d_in[9];
    float* out = (float*)d_out;

    int N = in_sizes[0] / 128;
    int E = in_sizes[1] / 2;
    const int* srcp = ei;
    const int* dstp = ei + E;
    int nbuck = (N + 511) >> 9;               // 196 for N=100k

    char* w = (char*)d_ws;
    auto alloc = [&](size_t bytes) {
        void* p = (void*)w;
        w += (bytes + 255) & ~(size_t)255;
        return p;
    };
    unsigned short* h1b = (unsigned short*)alloc((size_t)N * 64 * 2);
    float* a_s1  = (float*)alloc((size_t)N * 8 * 4);
    float* a_d1  = (float*)alloc((size_t)N * 8 * 4);
    unsigned short* heb = (unsigned short*)alloc((size_t)N * 64 * 2);
    unsigned short* h2b = (unsigned short*)alloc((size_t)N * 16 * 2);
    float* a_s2b = (float*)alloc((size_t)N * 4);
    float* a_d2b = (float*)alloc((size_t)N * 4);
    int*   rowp  = (int*)alloc((size_t)(N + 1) * 4);
    int*   srcs  = (int*)alloc((size_t)E * 4);
    int*   gcur  = (int*)alloc((size_t)nbuck * 4);
    int*   buf   = (int*)alloc((size_t)nbuck * BCAP * 4);  // 12.85 MB

    hipMemsetAsync(gcur, 0, (size_t)nbuck * 4, stream);

    int bblk = (E + ECHUNK - 1) / ECHUNK;
    bucket_kernel<<<bblk, 256, 0, stream>>>(srcp, dstp, gcur, buf, E, nbuck);
    csr_bucket_kernel<<<nbuck, 1024, 0, stream>>>(gcur, buf, rowp, srcs, N, E);

    int g1blocks = (N + 63) >> 6;
    gemm1_mfma_kernel<<<g1blocks, 256, 0, stream>>>(x, W1, as1, ad1, h1b, a_s1, a_d1, N);
    agg1_kernel<<<(N + 3) / 4, 256, 0, stream>>>(h1b, a_s1, a_d1, rowp, srcs, b1, heb, N);
    gemm2_kernel<<<512, 256, 0, stream>>>(heb, W2, as2, ad2, h2b, a_s2b, a_d2b, N);
    agg2_kernel<<<(N + 3) / 4, 256, 0, stream>>>(h2b, a_s2b, a_d2b, rowp, srcs, b2, out, N);
}

// Round 4
// 277.960 us; speedup vs baseline: 1.0163x; 1.0163x over previous
//
#include <hip/hip_runtime.h>
#include <hip/hip_bf16.h>

// ---------------------------------------------------------------------------
// 2-layer GAT (PyG GATConv semantics, eval mode, self-loops appended).
//   1) bucket (dst>>9, LDS-staged bucket-ordered writes -> coalesced runs)
//      -> csr_bucket (512-node buckets, 1024 thr + int4 sweeps, R1)
//   2) gemm1 (MFMA 16x16x32 bf16): h1 = x @ W1 -> bf16 + a_s/a_d epilogue
//   3) agg1: additive exp(v-8) agg, 16 lanes/edge ushort4 (R11 verified 59.8us)
//      R3: split into 2 half-range dispatches (node0 arg) — diagnostic, lets
//      the true #2/#3 kernels surface in the rocprof top-5.
//   4) gemm2: he @ W2 -> bf16 + a_s2/a_d2 epilogue (separate kernel)
//   5) agg2: additive agg, 4 lanes/edge ushort4 + fused log_softmax
// Lessons encoded:
//   R8  - never co-schedule scatter/atomic and MFMA personalities in one grid.
//   R10 - keep per-lane gather staging <= 8 B (ushort4), else the
//         occupancy-targeted VGPR budget serializes the gathers.
//   R12 - do NOT fuse gemm2 into agg1: any epilogue fattening (VGPR 24->28)
//         makes the allocator restructure the gather loop (3x confirmed).
//   R14 - bucket writes staged through LDS so each bucket's entries leave the
//         block as one contiguous run (~84 B) instead of 4 B random scatters.
//   R1(this session) - csr_bucket widened to 1024 thr + int4 loads (-8us).
//   R2(this session) - ECHUNK 4096->2048 REGRESSED (+4.5us: 2x gcur atomics,
//         half-length write runs). Reverted; ECHUNK=4096 is the verified point.
// ---------------------------------------------------------------------------

#define NEG_SLOPE 0.2f
#define EPS_DEN 1e-16f
#define CSHIFT 8.0f          // shift-invariant softmax; |logit| <~ 9 here
#define NBUCK_MAX 256
#define BCAP 16384
#define ECHUNK 4096          // edges per bucket block (16 per thread)
#define G1_PITCH 136

typedef __attribute__((ext_vector_type(8))) short bf16x8;
typedef __attribute__((ext_vector_type(4))) float f32x4;

__device__ __forceinline__ float bf2f(unsigned short u) {
    return __uint_as_float(((unsigned)u) << 16);
}
__device__ __forceinline__ unsigned short f2bf(float f) {
    unsigned x = __float_as_uint(f);
    unsigned r = x + 0x7fffu + ((x >> 16) & 1u);
    return (unsigned short)(r >> 16);
}

// ---------------- CSR build ----------------

// bucket by dst>>9; entries staged bucket-ordered in LDS, copied out in
// per-bucket contiguous runs (avg ~21 entries = 84 B) for write coalescing.
__global__ __launch_bounds__(256) void bucket_kernel(
    const int* __restrict__ src, const int* __restrict__ dst,
    int* __restrict__ gcur, int* __restrict__ buf, int E, int nbuck)
{
    __shared__ int cnt[NBUCK_MAX];       // counts -> placement cursors
    __shared__ int loff[NBUCK_MAX];      // local exclusive offsets
    __shared__ int offs[NBUCK_MAX];      // global segment base per bucket
    __shared__ int wsum[4];
    __shared__ int ldata[ECHUNK];        // packed entries, bucket-ordered
    __shared__ unsigned char bid[ECHUNK];// bucket id per slot (nbuck <= 256)
    int tid = threadIdx.x, lane = tid & 63, wv = tid >> 6;
    for (int i = tid; i < nbuck; i += 256) cnt[i] = 0;
    __syncthreads();
    int base = blockIdx.x * ECHUNK;
    int lim = min(base + ECHUNK, E);
    int dl[16];                          // ECHUNK == 256*16
#pragma unroll
    for (int k = 0; k < 16; ++k) {
        int e = base + tid + 256 * k;
        dl[k] = (e < lim) ? dst[e] : -1;
    }
#pragma unroll
    for (int k = 0; k < 16; ++k)
        if (dl[k] >= 0) atomicAdd(&cnt[dl[k] >> 9], 1);
    __syncthreads();
    // 256-wide exclusive scan of counts (thread t <-> bucket t)
    int c = (tid < nbuck) ? cnt[tid] : 0;
    int sc = c;
#pragma unroll
    for (int off = 1; off < 64; off <<= 1) {
        int o = __shfl_up(sc, off);
        if (lane >= off) sc += o;
    }
    if (lane == 63) wsum[wv] = sc;
    __syncthreads();
    if (tid == 0) {
        int acc = 0;
#pragma unroll
        for (int k = 0; k < 4; ++k) { int t = wsum[k]; wsum[k] = acc; acc += t; }
    }
    __syncthreads();
    if (tid < nbuck) {
        loff[tid] = wsum[wv] + sc - c;
        offs[tid] = atomicAdd(&gcur[tid], c);
        cnt[tid] = 0;                    // reuse as placement cursor
    }
    __syncthreads();
    // place entries bucket-ordered in LDS
#pragma unroll
    for (int k = 0; k < 16; ++k) {
        if (dl[k] >= 0) {
            int e = base + tid + 256 * k;
            int b = dl[k] >> 9;
            int slot = loff[b] + atomicAdd(&cnt[b], 1);
            ldata[slot] = (src[e] << 9) | (dl[k] & 511);
            bid[slot] = (unsigned char)b;
        }
    }
    __syncthreads();
    // copy out: consecutive slots in a bucket -> consecutive global dests
    int total = lim - base;
    for (int i = tid; i < total; i += 256) {
        int b = bid[i];
        int o = offs[b] + (i - loff[b]);
        if (o < BCAP) buf[(size_t)b * BCAP + o] = ldata[i];
    }
}

// per-512-node-bucket hist + scan + place.
// R1: 1024 threads (16 waves) + int4 sweeps — the 256-thr version was
// latency-bound at 196 blocks (<1 block/CU, 32 serial sweep iterations).
__global__ __launch_bounds__(1024) void csr_bucket_kernel(
    const int* __restrict__ gcur, const int* __restrict__ buf,
    int* __restrict__ rowptr, int* __restrict__ srcs, int N, int E)
{
    __shared__ int cnt[512];
    __shared__ int wsum[16];
    __shared__ int wbase[8];
    __shared__ int basesh;
    int b = blockIdx.x, tid = threadIdx.x;
    int lane = tid & 63, wv = tid >> 6;      // wv in 0..15
    if (tid < 512) cnt[tid] = 0;
    // inline prefix: base = sum_{i<b} gcur[i]  (<=196 L2-hot ints, 1 sweep)
    int part = 0;
    for (int i = tid; i < b; i += 1024) part += gcur[i];
#pragma unroll
    for (int off = 32; off >= 1; off >>= 1) part += __shfl_xor(part, off);
    if (lane == 0) wsum[wv] = part;
    __syncthreads();
    if (tid == 0) {
        int acc = 0;
#pragma unroll
        for (int k = 0; k < 16; ++k) acc += wsum[k];
        basesh = acc;
    }
    __syncthreads();
    int n = min(gcur[b], BCAP);
    const int* p = buf + (size_t)b * BCAP;
    const int4* p4 = (const int4*)p;         // 64 KiB-aligned segment
    int n4 = n >> 2;
    // phase 1: histogram (int4-vectorized, ~2 sweeps at 1024 thr)
    for (int i = tid; i < n4; i += 1024) {
        int4 v = p4[i];
        atomicAdd(&cnt[v.x & 511], 1);
        atomicAdd(&cnt[v.y & 511], 1);
        atomicAdd(&cnt[v.z & 511], 1);
        atomicAdd(&cnt[v.w & 511], 1);
    }
    for (int i = (n4 << 2) + tid; i < n; i += 1024)
        atomicAdd(&cnt[p[i] & 511], 1);
    __syncthreads();
    // scan of 512 counters on the first 8 waves (thread t <-> counter t)
    int c = (tid < 512) ? cnt[tid] : 0;
    int sc = c;
#pragma unroll
    for (int off = 1; off < 64; off <<= 1) {
        int o = __shfl_up(sc, off);
        if (lane >= off) sc += o;
    }
    if (lane == 63 && wv < 8) wsum[wv] = sc;
    __syncthreads();
    if (tid == 0) {
        int acc = 0;
#pragma unroll
        for (int k = 0; k < 8; ++k) { wbase[k] = acc; acc += wsum[k]; }
    }
    __syncthreads();
    if (tid < 512) {
        int g0 = basesh + wbase[wv] + (sc - c);   // exclusive prefix
        int node0 = (b << 9) + tid;
        if (node0 < N) rowptr[node0] = g0;
        cnt[tid] = g0;                            // placement cursor
    }
    __syncthreads();
    // phase 2: place (int4-vectorized)
    for (int i = tid; i < n4; i += 1024) {
        int4 v = p4[i];
        int px = atomicAdd(&cnt[v.x & 511], 1); srcs[px] = v.x >> 9;
        int py = atomicAdd(&cnt[v.y & 511], 1); srcs[py] = v.y >> 9;
        int pz = atomicAdd(&cnt[v.z & 511], 1); srcs[pz] = v.z >> 9;
        int pw = atomicAdd(&cnt[v.w & 511], 1); srcs[pw] = v.w >> 9;
    }
    for (int i = (n4 << 2) + tid; i < n; i += 1024) {
        int v = p[i];
        int posi = atomicAdd(&cnt[v & 511], 1);
        srcs[posi] = v >> 9;
    }
    if (b == 0 && tid == 0) rowptr[N] = E;
}

// ---------------- GEMM1 (MFMA): [N,128] @ [128,64] -> bf16 -------------------

__global__ __launch_bounds__(256) void gemm1_mfma_kernel(
    const float* __restrict__ x, const float* __restrict__ W1,
    const float* __restrict__ att_s, const float* __restrict__ att_d,
    unsigned short* __restrict__ h1b, float* __restrict__ a_s,
    float* __restrict__ a_d, int N)
{
    __shared__ unsigned short As[64 * G1_PITCH];
    __shared__ unsigned short Cs[64 * 68];
    int tid = threadIdx.x;
    int lane = tid & 63, wv = tid >> 6;
    int quad = lane >> 4, l16 = lane & 15;

    bf16x8 Bf[4][4];
#pragma unroll
    for (int ks = 0; ks < 4; ++ks)
#pragma unroll
        for (int nt = 0; nt < 4; ++nt) {
            bf16x8 f;
#pragma unroll
            for (int j = 0; j < 8; ++j)
                f[j] = (short)f2bf(W1[(ks * 32 + quad * 8 + j) * 64 + nt * 16 + l16]);
            Bf[ks][nt] = f;
        }
    float asw[4], adw[4];
#pragma unroll
    for (int nt = 0; nt < 4; ++nt) {
        asw[nt] = att_s[nt * 16 + l16];
        adw[nt] = att_d[nt * 16 + l16];
    }

    int nblocks = (N + 63) >> 6;
    for (int blk = blockIdx.x; blk < nblocks; blk += gridDim.x) {
        int row0 = blk << 6;
        __syncthreads();
#pragma unroll
        for (int i = 0; i < 8; ++i) {
            int idx = tid + 256 * i;
            int r = idx >> 5, c4 = idx & 31;
            int row = row0 + r;
            float4 v = (row < N) ? ((const float4*)x)[(size_t)row * 32 + c4]
                                 : make_float4(0.f, 0.f, 0.f, 0.f);
            ushort4 u;
            u.x = f2bf(v.x); u.y = f2bf(v.y); u.z = f2bf(v.z); u.w = f2bf(v.w);
            *(ushort4*)&As[r * G1_PITCH + c4 * 4] = u;
        }
        __syncthreads();
        f32x4 acc[4];
#pragma unroll
        for (int nt = 0; nt < 4; ++nt) acc[nt] = (f32x4){0.f, 0.f, 0.f, 0.f};
#pragma unroll
        for (int ks = 0; ks < 4; ++ks) {
            bf16x8 Af = *(const bf16x8*)&As[(wv * 16 + l16) * G1_PITCH + ks * 32 + quad * 8];
#pragma unroll
            for (int nt = 0; nt < 4; ++nt)
                acc[nt] = __builtin_amdgcn_mfma_f32_16x16x32_bf16(Af, Bf[ks][nt], acc[nt], 0, 0, 0);
        }
        int lrow = wv * 16 + quad * 4;
#pragma unroll
        for (int nt = 0; nt < 4; ++nt) {
            float ps[4], pd[4];
#pragma unroll
            for (int r = 0; r < 4; ++r) {
                ps[r] = acc[nt][r] * asw[nt];
                pd[r] = acc[nt][r] * adw[nt];
            }
#pragma unroll
            for (int off = 1; off < 8; off <<= 1)
#pragma unroll
                for (int r = 0; r < 4; ++r) {
                    ps[r] += __shfl_xor(ps[r], off);
                    pd[r] += __shfl_xor(pd[r], off);
                }
            if ((l16 & 7) == 0) {
                int head = nt * 2 + (l16 >> 3);
#pragma unroll
                for (int r = 0; r < 4; ++r) {
                    int row = row0 + lrow + r;
                    if (row < N) {
                        a_s[row * 8 + head] = ps[r];
                        a_d[row * 8 + head] = pd[r];
                    }
                }
            }
        }
#pragma unroll
        for (int nt = 0; nt < 4; ++nt)
#pragma unroll
            for (int r = 0; r < 4; ++r)
                Cs[(lrow + r) * 68 + nt * 16 + l16] = f2bf(acc[nt][r]);
        __syncthreads();
#pragma unroll
        for (int i = 0; i < 4; ++i) {
            int idx = tid + 256 * i;
            int r = idx >> 4, c4 = idx & 15;
            int row = row0 + r;
            if (row < N) {
                ushort4 u = *(const ushort4*)&Cs[r * 68 + c4 * 4];
                ((ushort4*)h1b)[(size_t)row * 16 + c4] = u;
            }
        }
    }
}

// ---------------- agg1: additive exp(v-8) agg, 16 edges in flight ------------
// q=lane>>4 edge-group (stride 4), pos=lane&15 -> channels 4pos..4pos+3,
// head hp=pos>>1. R11-verified 59.8us shape — do not fatten this kernel.
// R3: node0 offset arg so the grid can be split into 2 dispatches
// (diagnostic; internals unchanged).

__global__ __launch_bounds__(256) void agg1_kernel(
    const unsigned short* __restrict__ h1b, const float* __restrict__ a_s,
    const float* __restrict__ a_d, const int* __restrict__ rowptr,
    const int* __restrict__ srcs, const float* __restrict__ b1,
    unsigned short* __restrict__ heb, int node0, int N)
{
    int lane = threadIdx.x & 63, wid = threadIdx.x >> 6;
    int node = node0 + blockIdx.x * 4 + wid;
    if (node >= N) return;
    int q = lane >> 4, pos = lane & 15, hp = pos >> 1;
    int beg = rowptr[node], end = rowptr[node + 1];
    float adn = a_d[node * 8 + hp];
    const ushort4* h1v = (const ushort4*)h1b;    // row stride 16 ushort4

    float l = 0.f, a0 = 0.f, a1 = 0.f, a2 = 0.f, a3 = 0.f;
    if (q == 0) {                                // self-loop in group 0
        float v = a_s[node * 8 + hp] + adn;
        v = fmaxf(v, NEG_SLOPE * v);
        float p = __expf(v - CSHIFT);
        ushort4 h = h1v[(size_t)node * 16 + pos];
        l = p;
        a0 = p * bf2f(h.x); a1 = p * bf2f(h.y);
        a2 = p * bf2f(h.z); a3 = p * bf2f(h.w);
    }
    int e = beg + q;
    for (; e + 12 < end; e += 16) {
        int s0 = srcs[e], s1 = srcs[e + 4], s2 = srcs[e + 8], s3 = srcs[e + 12];
        float va0 = a_s[s0 * 8 + hp], va1 = a_s[s1 * 8 + hp];
        float va2 = a_s[s2 * 8 + hp], va3 = a_s[s3 * 8 + hp];
        ushort4 h0 = h1v[(size_t)s0 * 16 + pos];
        ushort4 h1_ = h1v[(size_t)s1 * 16 + pos];
        ushort4 h2_ = h1v[(size_t)s2 * 16 + pos];
        ushort4 h3_ = h1v[(size_t)s3 * 16 + pos];
        float v0 = va0 + adn; v0 = fmaxf(v0, NEG_SLOPE * v0);
        float v1 = va1 + adn; v1 = fmaxf(v1, NEG_SLOPE * v1);
        float v2 = va2 + adn; v2 = fmaxf(v2, NEG_SLOPE * v2);
        float v3 = va3 + adn; v3 = fmaxf(v3, NEG_SLOPE * v3);
        float p0 = __expf(v0 - CSHIFT), p1 = __expf(v1 - CSHIFT);
        float p2 = __expf(v2 - CSHIFT), p3 = __expf(v3 - CSHIFT);
        l += p0 + p1 + p2 + p3;
        a0 = fmaf(p0, bf2f(h0.x), a0); a1 = fmaf(p0, bf2f(h0.y), a1);
        a2 = fmaf(p0, bf2f(h0.z), a2); a3 = fmaf(p0, bf2f(h0.w), a3);
        a0 = fmaf(p1, bf2f(h1_.x), a0); a1 = fmaf(p1, bf2f(h1_.y), a1);
        a2 = fmaf(p1, bf2f(h1_.z), a2); a3 = fmaf(p1, bf2f(h1_.w), a3);
        a0 = fmaf(p2, bf2f(h2_.x), a0); a1 = fmaf(p2, bf2f(h2_.y), a1);
        a2 = fmaf(p2, bf2f(h2_.z), a2); a3 = fmaf(p2, bf2f(h2_.w), a3);
        a0 = fmaf(p3, bf2f(h3_.x), a0); a1 = fmaf(p3, bf2f(h3_.y), a1);
        a2 = fmaf(p3, bf2f(h3_.z), a2); a3 = fmaf(p3, bf2f(h3_.w), a3);
    }
    for (; e < end; e += 4) {
        int s = srcs[e];
        float va = a_s[s * 8 + hp];
        ushort4 h = h1v[(size_t)s * 16 + pos];
        float v = va + adn; v = fmaxf(v, NEG_SLOPE * v);
        float p = __expf(v - CSHIFT);
        l += p;
        a0 = fmaf(p, bf2f(h.x), a0); a1 = fmaf(p, bf2f(h.y), a1);
        a2 = fmaf(p, bf2f(h.z), a2); a3 = fmaf(p, bf2f(h.w), a3);
    }
#pragma unroll
    for (int off = 16; off < 64; off <<= 1) {
        l  += __shfl_xor(l, off);
        a0 += __shfl_xor(a0, off); a1 += __shfl_xor(a1, off);
        a2 += __shfl_xor(a2, off); a3 += __shfl_xor(a3, off);
    }
    if (q == 0) {
        float inv = 1.f / (l + EPS_DEN);
        float4 bb = ((const float4*)b1)[pos];
        float o0 = fmaf(a0, inv, bb.x);
        float o1 = fmaf(a1, inv, bb.y);
        float o2 = fmaf(a2, inv, bb.z);
        float o3 = fmaf(a3, inv, bb.w);
        o0 = o0 > 0.f ? o0 : __expf(o0) - 1.f;   // ELU
        o1 = o1 > 0.f ? o1 : __expf(o1) - 1.f;
        o2 = o2 > 0.f ? o2 : __expf(o2) - 1.f;
        o3 = o3 > 0.f ? o3 : __expf(o3) - 1.f;
        ushort4 u;
        u.x = f2bf(o0); u.y = f2bf(o1); u.z = f2bf(o2); u.w = f2bf(o3);
        ((ushort4*)heb)[(size_t)node * 16 + pos] = u;
    }
}

// ---------------- GEMM2: [N,64] @ [64,16] -> bf16 + a_s2/a_d2 epilogue -------

__global__ __launch_bounds__(256) void gemm2_kernel(
    const unsigned short* __restrict__ heb, const float* __restrict__ W2,
    const float* __restrict__ att_s2, const float* __restrict__ att_d2,
    unsigned short* __restrict__ h2b, float* __restrict__ a_s2,
    float* __restrict__ a_d2, int N)
{
    __shared__ float xs[4][4 * 68];
    int lane = threadIdx.x & 63, wid = threadIdx.x >> 6;
    int sub = lane >> 4, c = lane & 15;
    float wcol[64];
#pragma unroll
    for (int k = 0; k < 64; ++k) wcol[k] = W2[k * 16 + c];
    float asw = att_s2[c], adw = att_d2[c];
    int groups = (N + 15) >> 4;
    int iters = (groups + gridDim.x - 1) / gridDim.x;
    for (int it = 0; it < iters; ++it) {
        int g = blockIdx.x + it * gridDim.x;
        int nb = g * 16 + wid * 4;
        __syncthreads();
        if (g < groups) {
#pragma unroll
            for (int i = 0; i < 4; ++i) {
                int n = nb + i;
                xs[wid][i * 68 + lane] = (n < N) ? bf2f(heb[(size_t)n * 64 + lane]) : 0.f;
            }
        }
        __syncthreads();
        if (g < groups) {
            int node = nb + sub;
            const float4* xv = (const float4*)&xs[wid][sub * 68];
            float acc = 0.f;
#pragma unroll
            for (int k4 = 0; k4 < 16; ++k4) {
                float4 v = xv[k4];
                acc += v.x * wcol[4 * k4 + 0] + v.y * wcol[4 * k4 + 1]
                     + v.z * wcol[4 * k4 + 2] + v.w * wcol[4 * k4 + 3];
            }
            if (node < N) {
                h2b[(size_t)node * 16 + c] = f2bf(acc);
                float rs = acc * asw, rd = acc * adw;
#pragma unroll
                for (int off = 1; off < 16; off <<= 1) {
                    rs += __shfl_xor(rs, off);
                    rd += __shfl_xor(rd, off);
                }
                if (c == 0) { a_s2[node] = rs; a_d2[node] = rd; }
            }
        }
    }
}

// ---------------- agg2: additive exp(v-8) agg + fused log_softmax ------------
// q=lane>>2 edge-group (stride 16), pos=lane&3 -> classes 4pos..4pos+3.

__global__ __launch_bounds__(256) void agg2_kernel(
    const unsigned short* __restrict__ h2b, const float* __restrict__ a_s2,
    const float* __restrict__ a_d2, const int* __restrict__ rowptr,
    const int* __restrict__ srcs, const float* __restrict__ b2,
    float* __restrict__ out, int N)
{
    int lane = threadIdx.x & 63, wid = threadIdx.x >> 6;
    int node = blockIdx.x * 4 + wid;
    if (node >= N) return;
    int q = lane >> 2, pos = lane & 3;
    int beg = rowptr[node], end = rowptr[node + 1];
    float adn = a_d2[node];
    const ushort4* h2v = (const ushort4*)h2b;    // row stride 4 ushort4

    float l = 0.f, a0 = 0.f, a1 = 0.f, a2 = 0.f, a3 = 0.f;
    if (q == 0) {                                // self-loop in group 0
        float v = a_s2[node] + adn;
        v = fmaxf(v, NEG_SLOPE * v);
        float p = __expf(v - CSHIFT);
        ushort4 h = h2v[(size_t)node * 4 + pos];
        l = p;
        a0 = p * bf2f(h.x); a1 = p * bf2f(h.y);
        a2 = p * bf2f(h.z); a3 = p * bf2f(h.w);
    }
    int e = beg + q;
    for (; e + 16 < end; e += 32) {
        int s0 = srcs[e], s1 = srcs[e + 16];
        float va0 = a_s2[s0], va1 = a_s2[s1];
        ushort4 h0 = h2v[(size_t)s0 * 4 + pos];
        ushort4 h1_ = h2v[(size_t)s1 * 4 + pos];
        float v0 = va0 + adn; v0 = fmaxf(v0, NEG_SLOPE * v0);
        float v1 = va1 + adn; v1 = fmaxf(v1, NEG_SLOPE * v1);
        float p0 = __expf(v0 - CSHIFT), p1 = __expf(v1 - CSHIFT);
        l += p0 + p1;
        a0 = fmaf(p0, bf2f(h0.x), a0); a1 = fmaf(p0, bf2f(h0.y), a1);
        a2 = fmaf(p0, bf2f(h0.z), a2); a3 = fmaf(p0, bf2f(h0.w), a3);
        a0 = fmaf(p1, bf2f(h1_.x), a0); a1 = fmaf(p1, bf2f(h1_.y), a1);
        a2 = fmaf(p1, bf2f(h1_.z), a2); a3 = fmaf(p1, bf2f(h1_.w), a3);
    }
    for (; e < end; e += 16) {
        int s = srcs[e];
        float va = a_s2[s];
        ushort4 h = h2v[(size_t)s * 4 + pos];
        float v = va + adn; v = fmaxf(v, NEG_SLOPE * v);
        float p = __expf(v - CSHIFT);
        l += p;
        a0 = fmaf(p, bf2f(h.x), a0); a1 = fmaf(p, bf2f(h.y), a1);
        a2 = fmaf(p, bf2f(h.z), a2); a3 = fmaf(p, bf2f(h.w), a3);
    }
#pragma unroll
    for (int off = 4; off < 64; off <<= 1) {
        l  += __shfl_xor(l, off);
        a0 += __shfl_xor(a0, off); a1 += __shfl_xor(a1, off);
        a2 += __shfl_xor(a2, off); a3 += __shfl_xor(a3, off);
    }
    if (q == 0) {
        float inv = 1.f / (l + EPS_DEN);
        float4 bb = ((const float4*)b2)[pos];
        float o0 = fmaf(a0, inv, bb.x);
        float o1 = fmaf(a1, inv, bb.y);
        float o2 = fmaf(a2, inv, bb.z);
        float o3 = fmaf(a3, inv, bb.w);
        float mx = fmaxf(fmaxf(o0, o1), fmaxf(o2, o3));
        mx = fmaxf(mx, __shfl_xor(mx, 1));
        mx = fmaxf(mx, __shfl_xor(mx, 2));
        float se = __expf(o0 - mx) + __expf(o1 - mx)
                 + __expf(o2 - mx) + __expf(o3 - mx);
        se += __shfl_xor(se, 1);
        se += __shfl_xor(se, 2);
        float ls = mx + logf(se);
        ((float4*)out)[(size_t)node * 4 + pos] =
            make_float4(o0 - ls, o1 - ls, o2 - ls, o3 - ls);
    }
}

// ---------------------------------------------------------------------------

extern "C" void kernel_launch(void* const* d_in, const int* in_sizes, int n_in,
                              void* d_out, int out_size, void* d_ws, size_t ws_size,
                              hipStream_t stream) {
    const float* x    = (const float*)d_in[0];
    const int*   ei   = (const int*)d_in[1];
    const float* W1   = (const float*)d_in[2];
    const float* b1   = (const float*)d_in[3];
    const float* as1  = (const float*)d_in[4];
    const float* ad1  = (const float*)d_in[5];
    const float* W2   = (const float*)d_in[6];
    const float* b2   = (const float*)d_in[7];
    const float* as2  = (const float*)d_in[8];
    const float* ad2  = (const float*)d_in[9];
    float* out = (float*)d_out;

    int N = in_sizes[0] / 128;
    int E = in_sizes[1] / 2;
    const int* srcp = ei;
    const int* dstp = ei + E;
    int nbuck = (N + 511) >> 9;               // 196 for N=100k

    char* w = (char*)d_ws;
    auto alloc = [&](size_t bytes) {
        void* p = (void*)w;
        w += (bytes + 255) & ~(size_t)255;
        return p;
    };
    unsigned short* h1b = (unsigned short*)alloc((size_t)N * 64 * 2);
    float* a_s1  = (float*)alloc((size_t)N * 8 * 4);
    float* a_d1  = (float*)alloc((size_t)N * 8 * 4);
    unsigned short* heb = (unsigned short*)alloc((size_t)N * 64 * 2);
    unsigned short* h2b = (unsigned short*)alloc((size_t)N * 16 * 2);
    float* a_s2b = (float*)alloc((size_t)N * 4);
    float* a_d2b = (float*)alloc((size_t)N * 4);
    int*   rowp  = (int*)alloc((size_t)(N + 1) * 4);
    int*   srcs  = (int*)alloc((size_t)E * 4);
    int*   gcur  = (int*)alloc((size_t)nbuck * 4);
    int*   buf   = (int*)alloc((size_t)nbuck * BCAP * 4);  // 12.85 MB

    hipMemsetAsync(gcur, 0, (size_t)nbuck * 4, stream);

    int bblk = (E + ECHUNK - 1) / ECHUNK;
    bucket_kernel<<<bblk, 256, 0, stream>>>(srcp, dstp, gcur, buf, E, nbuck);
    csr_bucket_kernel<<<nbuck, 1024, 0, stream>>>(gcur, buf, rowp, srcs, N, E);

    int g1blocks = (N + 63) >> 6;
    gemm1_mfma_kernel<<<g1blocks, 256, 0, stream>>>(x, W1, as1, ad1, h1b, a_s1, a_d1, N);

    // R3: agg1 split into two half-range dispatches (diagnostic — surfaces
    // the true #2/#3 kernels in rocprof top-5; internals unchanged).
    int half = ((N / 2) + 3) & ~3;            // multiple of 4
    agg1_kernel<<<(half + 3) / 4, 256, 0, stream>>>(h1b, a_s1, a_d1, rowp, srcs, b1, heb, 0, half);
    agg1_kernel<<<((N - half) + 3) / 4, 256, 0, stream>>>(h1b, a_s1, a_d1, rowp, srcs, b1, heb, half, N);

    gemm2_kernel<<<512, 256, 0, stream>>>(heb, W2, as2, ad2, h2b, a_s2b, a_d2b, N);
    agg2_kernel<<<(N + 3) / 4, 256, 0, stream>>>(h2b, a_s2b, a_d2b, rowp, srcs, b2, out, N);
}

// Round 5
// 266.775 us; speedup vs baseline: 1.0589x; 1.0419x over previous
//
#include <hip/hip_runtime.h>
#include <hip/hip_bf16.h>

// ---------------------------------------------------------------------------
// 2-layer GAT (PyG GATConv semantics, eval mode, self-loops appended).
//   1) bucket (dst>>9, LDS-staged bucket-ordered writes -> coalesced runs)
//      -> csr_bucket (512-node buckets, 1024 thr + int4 sweeps, R1)
//   2) gemm1 (MFMA 16x16x32 bf16): h1 = x @ W1 -> bf16 + a_s/a_d epilogue
//   3) agg1: additive exp(v-8) agg, 16 lanes/edge ushort4 (R11 verified 59.8us)
//      R3: split into 2 half-range dispatches (node0 arg) — diagnostic.
//   4) gemm2: he @ W2 -> bf16 + a_s2/a_d2 epilogue (separate kernel)
//   5) agg2: R4 — 4 nodes/wave, 16 lanes/node (was 1 node/wave: with deg~17
//      and 16 edge-groups, the 4-level x5-value shfl tree per node dominated;
//      VALUBusy 65% at only 10% HBM). 2-level reduction serves 4 nodes/wave.
// Lessons encoded:
//   R8  - never co-schedule scatter/atomic and MFMA personalities in one grid.
//   R10 - keep per-lane gather staging <= 8 B (ushort4), else the
//         occupancy-targeted VGPR budget serializes the gathers.
//   R12 - do NOT fuse gemm2 into agg1: any epilogue fattening (VGPR 24->28)
//         makes the allocator restructure the gather loop (3x confirmed).
//   R14 - bucket writes staged through LDS so each bucket's entries leave the
//         block as one contiguous run (~84 B) instead of 4 B random scatters.
//   R1(this session) - csr_bucket widened to 1024 thr + int4 loads (-8us).
//   R2(this session) - ECHUNK 4096->2048 REGRESSED (+4.5us). ECHUNK=4096.
// ---------------------------------------------------------------------------

#define NEG_SLOPE 0.2f
#define EPS_DEN 1e-16f
#define CSHIFT 8.0f          // shift-invariant softmax; |logit| <~ 9 here
#define NBUCK_MAX 256
#define BCAP 16384
#define ECHUNK 4096          // edges per bucket block (16 per thread)
#define G1_PITCH 136

typedef __attribute__((ext_vector_type(8))) short bf16x8;
typedef __attribute__((ext_vector_type(4))) float f32x4;

__device__ __forceinline__ float bf2f(unsigned short u) {
    return __uint_as_float(((unsigned)u) << 16);
}
__device__ __forceinline__ unsigned short f2bf(float f) {
    unsigned x = __float_as_uint(f);
    unsigned r = x + 0x7fffu + ((x >> 16) & 1u);
    return (unsigned short)(r >> 16);
}

// ---------------- CSR build ----------------

// bucket by dst>>9; entries staged bucket-ordered in LDS, copied out in
// per-bucket contiguous runs (avg ~21 entries = 84 B) for write coalescing.
__global__ __launch_bounds__(256) void bucket_kernel(
    const int* __restrict__ src, const int* __restrict__ dst,
    int* __restrict__ gcur, int* __restrict__ buf, int E, int nbuck)
{
    __shared__ int cnt[NBUCK_MAX];       // counts -> placement cursors
    __shared__ int loff[NBUCK_MAX];      // local exclusive offsets
    __shared__ int offs[NBUCK_MAX];      // global segment base per bucket
    __shared__ int wsum[4];
    __shared__ int ldata[ECHUNK];        // packed entries, bucket-ordered
    __shared__ unsigned char bid[ECHUNK];// bucket id per slot (nbuck <= 256)
    int tid = threadIdx.x, lane = tid & 63, wv = tid >> 6;
    for (int i = tid; i < nbuck; i += 256) cnt[i] = 0;
    __syncthreads();
    int base = blockIdx.x * ECHUNK;
    int lim = min(base + ECHUNK, E);
    int dl[16];                          // ECHUNK == 256*16
#pragma unroll
    for (int k = 0; k < 16; ++k) {
        int e = base + tid + 256 * k;
        dl[k] = (e < lim) ? dst[e] : -1;
    }
#pragma unroll
    for (int k = 0; k < 16; ++k)
        if (dl[k] >= 0) atomicAdd(&cnt[dl[k] >> 9], 1);
    __syncthreads();
    // 256-wide exclusive scan of counts (thread t <-> bucket t)
    int c = (tid < nbuck) ? cnt[tid] : 0;
    int sc = c;
#pragma unroll
    for (int off = 1; off < 64; off <<= 1) {
        int o = __shfl_up(sc, off);
        if (lane >= off) sc += o;
    }
    if (lane == 63) wsum[wv] = sc;
    __syncthreads();
    if (tid == 0) {
        int acc = 0;
#pragma unroll
        for (int k = 0; k < 4; ++k) { int t = wsum[k]; wsum[k] = acc; acc += t; }
    }
    __syncthreads();
    if (tid < nbuck) {
        loff[tid] = wsum[wv] + sc - c;
        offs[tid] = atomicAdd(&gcur[tid], c);
        cnt[tid] = 0;                    // reuse as placement cursor
    }
    __syncthreads();
    // place entries bucket-ordered in LDS
#pragma unroll
    for (int k = 0; k < 16; ++k) {
        if (dl[k] >= 0) {
            int e = base + tid + 256 * k;
            int b = dl[k] >> 9;
            int slot = loff[b] + atomicAdd(&cnt[b], 1);
            ldata[slot] = (src[e] << 9) | (dl[k] & 511);
            bid[slot] = (unsigned char)b;
        }
    }
    __syncthreads();
    // copy out: consecutive slots in a bucket -> consecutive global dests
    int total = lim - base;
    for (int i = tid; i < total; i += 256) {
        int b = bid[i];
        int o = offs[b] + (i - loff[b]);
        if (o < BCAP) buf[(size_t)b * BCAP + o] = ldata[i];
    }
}

// per-512-node-bucket hist + scan + place.
// R1: 1024 threads (16 waves) + int4 sweeps — the 256-thr version was
// latency-bound at 196 blocks (<1 block/CU, 32 serial sweep iterations).
__global__ __launch_bounds__(1024) void csr_bucket_kernel(
    const int* __restrict__ gcur, const int* __restrict__ buf,
    int* __restrict__ rowptr, int* __restrict__ srcs, int N, int E)
{
    __shared__ int cnt[512];
    __shared__ int wsum[16];
    __shared__ int wbase[8];
    __shared__ int basesh;
    int b = blockIdx.x, tid = threadIdx.x;
    int lane = tid & 63, wv = tid >> 6;      // wv in 0..15
    if (tid < 512) cnt[tid] = 0;
    // inline prefix: base = sum_{i<b} gcur[i]  (<=196 L2-hot ints, 1 sweep)
    int part = 0;
    for (int i = tid; i < b; i += 1024) part += gcur[i];
#pragma unroll
    for (int off = 32; off >= 1; off >>= 1) part += __shfl_xor(part, off);
    if (lane == 0) wsum[wv] = part;
    __syncthreads();
    if (tid == 0) {
        int acc = 0;
#pragma unroll
        for (int k = 0; k < 16; ++k) acc += wsum[k];
        basesh = acc;
    }
    __syncthreads();
    int n = min(gcur[b], BCAP);
    const int* p = buf + (size_t)b * BCAP;
    const int4* p4 = (const int4*)p;         // 64 KiB-aligned segment
    int n4 = n >> 2;
    // phase 1: histogram (int4-vectorized, ~2 sweeps at 1024 thr)
    for (int i = tid; i < n4; i += 1024) {
        int4 v = p4[i];
        atomicAdd(&cnt[v.x & 511], 1);
        atomicAdd(&cnt[v.y & 511], 1);
        atomicAdd(&cnt[v.z & 511], 1);
        atomicAdd(&cnt[v.w & 511], 1);
    }
    for (int i = (n4 << 2) + tid; i < n; i += 1024)
        atomicAdd(&cnt[p[i] & 511], 1);
    __syncthreads();
    // scan of 512 counters on the first 8 waves (thread t <-> counter t)
    int c = (tid < 512) ? cnt[tid] : 0;
    int sc = c;
#pragma unroll
    for (int off = 1; off < 64; off <<= 1) {
        int o = __shfl_up(sc, off);
        if (lane >= off) sc += o;
    }
    if (lane == 63 && wv < 8) wsum[wv] = sc;
    __syncthreads();
    if (tid == 0) {
        int acc = 0;
#pragma unroll
        for (int k = 0; k < 8; ++k) { wbase[k] = acc; acc += wsum[k]; }
    }
    __syncthreads();
    if (tid < 512) {
        int g0 = basesh + wbase[wv] + (sc - c);   // exclusive prefix
        int node0 = (b << 9) + tid;
        if (node0 < N) rowptr[node0] = g0;
        cnt[tid] = g0;                            // placement cursor
    }
    __syncthreads();
    // phase 2: place (int4-vectorized)
    for (int i = tid; i < n4; i += 1024) {
        int4 v = p4[i];
        int px = atomicAdd(&cnt[v.x & 511], 1); srcs[px] = v.x >> 9;
        int py = atomicAdd(&cnt[v.y & 511], 1); srcs[py] = v.y >> 9;
        int pz = atomicAdd(&cnt[v.z & 511], 1); srcs[pz] = v.z >> 9;
        int pw = atomicAdd(&cnt[v.w & 511], 1); srcs[pw] = v.w >> 9;
    }
    for (int i = (n4 << 2) + tid; i < n; i += 1024) {
        int v = p[i];
        int posi = atomicAdd(&cnt[v & 511], 1);
        srcs[posi] = v >> 9;
    }
    if (b == 0 && tid == 0) rowptr[N] = E;
}

// ---------------- GEMM1 (MFMA): [N,128] @ [128,64] -> bf16 -------------------

__global__ __launch_bounds__(256) void gemm1_mfma_kernel(
    const float* __restrict__ x, const float* __restrict__ W1,
    const float* __restrict__ att_s, const float* __restrict__ att_d,
    unsigned short* __restrict__ h1b, float* __restrict__ a_s,
    float* __restrict__ a_d, int N)
{
    __shared__ unsigned short As[64 * G1_PITCH];
    __shared__ unsigned short Cs[64 * 68];
    int tid = threadIdx.x;
    int lane = tid & 63, wv = tid >> 6;
    int quad = lane >> 4, l16 = lane & 15;

    bf16x8 Bf[4][4];
#pragma unroll
    for (int ks = 0; ks < 4; ++ks)
#pragma unroll
        for (int nt = 0; nt < 4; ++nt) {
            bf16x8 f;
#pragma unroll
            for (int j = 0; j < 8; ++j)
                f[j] = (short)f2bf(W1[(ks * 32 + quad * 8 + j) * 64 + nt * 16 + l16]);
            Bf[ks][nt] = f;
        }
    float asw[4], adw[4];
#pragma unroll
    for (int nt = 0; nt < 4; ++nt) {
        asw[nt] = att_s[nt * 16 + l16];
        adw[nt] = att_d[nt * 16 + l16];
    }

    int nblocks = (N + 63) >> 6;
    for (int blk = blockIdx.x; blk < nblocks; blk += gridDim.x) {
        int row0 = blk << 6;
        __syncthreads();
#pragma unroll
        for (int i = 0; i < 8; ++i) {
            int idx = tid + 256 * i;
            int r = idx >> 5, c4 = idx & 31;
            int row = row0 + r;
            float4 v = (row < N) ? ((const float4*)x)[(size_t)row * 32 + c4]
                                 : make_float4(0.f, 0.f, 0.f, 0.f);
            ushort4 u;
            u.x = f2bf(v.x); u.y = f2bf(v.y); u.z = f2bf(v.z); u.w = f2bf(v.w);
            *(ushort4*)&As[r * G1_PITCH + c4 * 4] = u;
        }
        __syncthreads();
        f32x4 acc[4];
#pragma unroll
        for (int nt = 0; nt < 4; ++nt) acc[nt] = (f32x4){0.f, 0.f, 0.f, 0.f};
#pragma unroll
        for (int ks = 0; ks < 4; ++ks) {
            bf16x8 Af = *(const bf16x8*)&As[(wv * 16 + l16) * G1_PITCH + ks * 32 + quad * 8];
#pragma unroll
            for (int nt = 0; nt < 4; ++nt)
                acc[nt] = __builtin_amdgcn_mfma_f32_16x16x32_bf16(Af, Bf[ks][nt], acc[nt], 0, 0, 0);
        }
        int lrow = wv * 16 + quad * 4;
#pragma unroll
        for (int nt = 0; nt < 4; ++nt) {
            float ps[4], pd[4];
#pragma unroll
            for (int r = 0; r < 4; ++r) {
                ps[r] = acc[nt][r] * asw[nt];
                pd[r] = acc[nt][r] * adw[nt];
            }
#pragma unroll
            for (int off = 1; off < 8; off <<= 1)
#pragma unroll
                for (int r = 0; r < 4; ++r) {
                    ps[r] += __shfl_xor(ps[r], off);
                    pd[r] += __shfl_xor(pd[r], off);
                }
            if ((l16 & 7) == 0) {
                int head = nt * 2 + (l16 >> 3);
#pragma unroll
                for (int r = 0; r < 4; ++r) {
                    int row = row0 + lrow + r;
                    if (row < N) {
                        a_s[row * 8 + head] = ps[r];
                        a_d[row * 8 + head] = pd[r];
                    }
                }
            }
        }
#pragma unroll
        for (int nt = 0; nt < 4; ++nt)
#pragma unroll
            for (int r = 0; r < 4; ++r)
                Cs[(lrow + r) * 68 + nt * 16 + l16] = f2bf(acc[nt][r]);
        __syncthreads();
#pragma unroll
        for (int i = 0; i < 4; ++i) {
            int idx = tid + 256 * i;
            int r = idx >> 4, c4 = idx & 15;
            int row = row0 + r;
            if (row < N) {
                ushort4 u = *(const ushort4*)&Cs[r * 68 + c4 * 4];
                ((ushort4*)h1b)[(size_t)row * 16 + c4] = u;
            }
        }
    }
}

// ---------------- agg1: additive exp(v-8) agg, 16 edges in flight ------------
// q=lane>>4 edge-group (stride 4), pos=lane&15 -> channels 4pos..4pos+3,
// head hp=pos>>1. R11-verified 59.8us shape — do not fatten this kernel.
// R3: node0 offset arg so the grid can be split into 2 dispatches
// (diagnostic; internals unchanged).

__global__ __launch_bounds__(256) void agg1_kernel(
    const unsigned short* __restrict__ h1b, const float* __restrict__ a_s,
    const float* __restrict__ a_d, const int* __restrict__ rowptr,
    const int* __restrict__ srcs, const float* __restrict__ b1,
    unsigned short* __restrict__ heb, int node0, int N)
{
    int lane = threadIdx.x & 63, wid = threadIdx.x >> 6;
    int node = node0 + blockIdx.x * 4 + wid;
    if (node >= N) return;
    int q = lane >> 4, pos = lane & 15, hp = pos >> 1;
    int beg = rowptr[node], end = rowptr[node + 1];
    float adn = a_d[node * 8 + hp];
    const ushort4* h1v = (const ushort4*)h1b;    // row stride 16 ushort4

    float l = 0.f, a0 = 0.f, a1 = 0.f, a2 = 0.f, a3 = 0.f;
    if (q == 0) {                                // self-loop in group 0
        float v = a_s[node * 8 + hp] + adn;
        v = fmaxf(v, NEG_SLOPE * v);
        float p = __expf(v - CSHIFT);
        ushort4 h = h1v[(size_t)node * 16 + pos];
        l = p;
        a0 = p * bf2f(h.x); a1 = p * bf2f(h.y);
        a2 = p * bf2f(h.z); a3 = p * bf2f(h.w);
    }
    int e = beg + q;
    for (; e + 12 < end; e += 16) {
        int s0 = srcs[e], s1 = srcs[e + 4], s2 = srcs[e + 8], s3 = srcs[e + 12];
        float va0 = a_s[s0 * 8 + hp], va1 = a_s[s1 * 8 + hp];
        float va2 = a_s[s2 * 8 + hp], va3 = a_s[s3 * 8 + hp];
        ushort4 h0 = h1v[(size_t)s0 * 16 + pos];
        ushort4 h1_ = h1v[(size_t)s1 * 16 + pos];
        ushort4 h2_ = h1v[(size_t)s2 * 16 + pos];
        ushort4 h3_ = h1v[(size_t)s3 * 16 + pos];
        float v0 = va0 + adn; v0 = fmaxf(v0, NEG_SLOPE * v0);
        float v1 = va1 + adn; v1 = fmaxf(v1, NEG_SLOPE * v1);
        float v2 = va2 + adn; v2 = fmaxf(v2, NEG_SLOPE * v2);
        float v3 = va3 + adn; v3 = fmaxf(v3, NEG_SLOPE * v3);
        float p0 = __expf(v0 - CSHIFT), p1 = __expf(v1 - CSHIFT);
        float p2 = __expf(v2 - CSHIFT), p3 = __expf(v3 - CSHIFT);
        l += p0 + p1 + p2 + p3;
        a0 = fmaf(p0, bf2f(h0.x), a0); a1 = fmaf(p0, bf2f(h0.y), a1);
        a2 = fmaf(p0, bf2f(h0.z), a2); a3 = fmaf(p0, bf2f(h0.w), a3);
        a0 = fmaf(p1, bf2f(h1_.x), a0); a1 = fmaf(p1, bf2f(h1_.y), a1);
        a2 = fmaf(p1, bf2f(h1_.z), a2); a3 = fmaf(p1, bf2f(h1_.w), a3);
        a0 = fmaf(p2, bf2f(h2_.x), a0); a1 = fmaf(p2, bf2f(h2_.y), a1);
        a2 = fmaf(p2, bf2f(h2_.z), a2); a3 = fmaf(p2, bf2f(h2_.w), a3);
        a0 = fmaf(p3, bf2f(h3_.x), a0); a1 = fmaf(p3, bf2f(h3_.y), a1);
        a2 = fmaf(p3, bf2f(h3_.z), a2); a3 = fmaf(p3, bf2f(h3_.w), a3);
    }
    for (; e < end; e += 4) {
        int s = srcs[e];
        float va = a_s[s * 8 + hp];
        ushort4 h = h1v[(size_t)s * 16 + pos];
        float v = va + adn; v = fmaxf(v, NEG_SLOPE * v);
        float p = __expf(v - CSHIFT);
        l += p;
        a0 = fmaf(p, bf2f(h.x), a0); a1 = fmaf(p, bf2f(h.y), a1);
        a2 = fmaf(p, bf2f(h.z), a2); a3 = fmaf(p, bf2f(h.w), a3);
    }
#pragma unroll
    for (int off = 16; off < 64; off <<= 1) {
        l  += __shfl_xor(l, off);
        a0 += __shfl_xor(a0, off); a1 += __shfl_xor(a1, off);
        a2 += __shfl_xor(a2, off); a3 += __shfl_xor(a3, off);
    }
    if (q == 0) {
        float inv = 1.f / (l + EPS_DEN);
        float4 bb = ((const float4*)b1)[pos];
        float o0 = fmaf(a0, inv, bb.x);
        float o1 = fmaf(a1, inv, bb.y);
        float o2 = fmaf(a2, inv, bb.z);
        float o3 = fmaf(a3, inv, bb.w);
        o0 = o0 > 0.f ? o0 : __expf(o0) - 1.f;   // ELU
        o1 = o1 > 0.f ? o1 : __expf(o1) - 1.f;
        o2 = o2 > 0.f ? o2 : __expf(o2) - 1.f;
        o3 = o3 > 0.f ? o3 : __expf(o3) - 1.f;
        ushort4 u;
        u.x = f2bf(o0); u.y = f2bf(o1); u.z = f2bf(o2); u.w = f2bf(o3);
        ((ushort4*)heb)[(size_t)node * 16 + pos] = u;
    }
}

// ---------------- GEMM2: [N,64] @ [64,16] -> bf16 + a_s2/a_d2 epilogue -------

__global__ __launch_bounds__(256) void gemm2_kernel(
    const unsigned short* __restrict__ heb, const float* __restrict__ W2,
    const float* __restrict__ att_s2, const float* __restrict__ att_d2,
    unsigned short* __restrict__ h2b, float* __restrict__ a_s2,
    float* __restrict__ a_d2, int N)
{
    __shared__ float xs[4][4 * 68];
    int lane = threadIdx.x & 63, wid = threadIdx.x >> 6;
    int sub = lane >> 4, c = lane & 15;
    float wcol[64];
#pragma unroll
    for (int k = 0; k < 64; ++k) wcol[k] = W2[k * 16 + c];
    float asw = att_s2[c], adw = att_d2[c];
    int groups = (N + 15) >> 4;
    int iters = (groups + gridDim.x - 1) / gridDim.x;
    for (int it = 0; it < iters; ++it) {
        int g = blockIdx.x + it * gridDim.x;
        int nb = g * 16 + wid * 4;
        __syncthreads();
        if (g < groups) {
#pragma unroll
            for (int i = 0; i < 4; ++i) {
                int n = nb + i;
                xs[wid][i * 68 + lane] = (n < N) ? bf2f(heb[(size_t)n * 64 + lane]) : 0.f;
            }
        }
        __syncthreads();
        if (g < groups) {
            int node = nb + sub;
            const float4* xv = (const float4*)&xs[wid][sub * 68];
            float acc = 0.f;
#pragma unroll
            for (int k4 = 0; k4 < 16; ++k4) {
                float4 v = xv[k4];
                acc += v.x * wcol[4 * k4 + 0] + v.y * wcol[4 * k4 + 1]
                     + v.z * wcol[4 * k4 + 2] + v.w * wcol[4 * k4 + 3];
            }
            if (node < N) {
                h2b[(size_t)node * 16 + c] = f2bf(acc);
                float rs = acc * asw, rd = acc * adw;
#pragma unroll
                for (int off = 1; off < 16; off <<= 1) {
                    rs += __shfl_xor(rs, off);
                    rd += __shfl_xor(rd, off);
                }
                if (c == 0) { a_s2[node] = rs; a_d2[node] = rd; }
            }
        }
    }
}

// ---------------- agg2: additive exp(v-8) agg + fused log_softmax ------------
// R4: 4 nodes/wave, 16 lanes/node. nsub=lane>>4 node, q=(lane>>2)&3 edge-group
// (stride 4), pos=lane&3 -> classes 4pos..4pos+3. 2-level shfl reduction
// (off 4,8) amortized over 4 nodes; deg~17/4 groups pipelines ~4 gathers/lane.

__global__ __launch_bounds__(256) void agg2_kernel(
    const unsigned short* __restrict__ h2b, const float* __restrict__ a_s2,
    const float* __restrict__ a_d2, const int* __restrict__ rowptr,
    const int* __restrict__ srcs, const float* __restrict__ b2,
    float* __restrict__ out, int N)
{
    int lane = threadIdx.x & 63, wid = threadIdx.x >> 6;
    int nsub = lane >> 4;
    int node = blockIdx.x * 16 + wid * 4 + nsub;
    if (node >= N) return;
    int q = (lane >> 2) & 3, pos = lane & 3;
    int beg = rowptr[node], end = rowptr[node + 1];
    float adn = a_d2[node];
    const ushort4* h2v = (const ushort4*)h2b;    // row stride 4 ushort4

    float l = 0.f, a0 = 0.f, a1 = 0.f, a2 = 0.f, a3 = 0.f;
    if (q == 0) {                                // self-loop in group 0
        float v = a_s2[node] + adn;
        v = fmaxf(v, NEG_SLOPE * v);
        float p = __expf(v - CSHIFT);
        ushort4 h = h2v[(size_t)node * 4 + pos];
        l = p;
        a0 = p * bf2f(h.x); a1 = p * bf2f(h.y);
        a2 = p * bf2f(h.z); a3 = p * bf2f(h.w);
    }
    int e = beg + q;
    for (; e + 4 < end; e += 8) {
        int s0 = srcs[e], s1 = srcs[e + 4];
        float va0 = a_s2[s0], va1 = a_s2[s1];
        ushort4 h0 = h2v[(size_t)s0 * 4 + pos];
        ushort4 h1_ = h2v[(size_t)s1 * 4 + pos];
        float v0 = va0 + adn; v0 = fmaxf(v0, NEG_SLOPE * v0);
        float v1 = va1 + adn; v1 = fmaxf(v1, NEG_SLOPE * v1);
        float p0 = __expf(v0 - CSHIFT), p1 = __expf(v1 - CSHIFT);
        l += p0 + p1;
        a0 = fmaf(p0, bf2f(h0.x), a0); a1 = fmaf(p0, bf2f(h0.y), a1);
        a2 = fmaf(p0, bf2f(h0.z), a2); a3 = fmaf(p0, bf2f(h0.w), a3);
        a0 = fmaf(p1, bf2f(h1_.x), a0); a1 = fmaf(p1, bf2f(h1_.y), a1);
        a2 = fmaf(p1, bf2f(h1_.z), a2); a3 = fmaf(p1, bf2f(h1_.w), a3);
    }
    for (; e < end; e += 4) {
        int s = srcs[e];
        float va = a_s2[s];
        ushort4 h = h2v[(size_t)s * 4 + pos];
        float v = va + adn; v = fmaxf(v, NEG_SLOPE * v);
        float p = __expf(v - CSHIFT);
        l += p;
        a0 = fmaf(p, bf2f(h.x), a0); a1 = fmaf(p, bf2f(h.y), a1);
        a2 = fmaf(p, bf2f(h.z), a2); a3 = fmaf(p, bf2f(h.w), a3);
    }
#pragma unroll
    for (int off = 4; off < 16; off <<= 1) {
        l  += __shfl_xor(l, off);
        a0 += __shfl_xor(a0, off); a1 += __shfl_xor(a1, off);
        a2 += __shfl_xor(a2, off); a3 += __shfl_xor(a3, off);
    }
    if (q == 0) {
        float inv = 1.f / (l + EPS_DEN);
        float4 bb = ((const float4*)b2)[pos];
        float o0 = fmaf(a0, inv, bb.x);
        float o1 = fmaf(a1, inv, bb.y);
        float o2 = fmaf(a2, inv, bb.z);
        float o3 = fmaf(a3, inv, bb.w);
        float mx = fmaxf(fmaxf(o0, o1), fmaxf(o2, o3));
        mx = fmaxf(mx, __shfl_xor(mx, 1));
        mx = fmaxf(mx, __shfl_xor(mx, 2));
        float se = __expf(o0 - mx) + __expf(o1 - mx)
                 + __expf(o2 - mx) + __expf(o3 - mx);
        se += __shfl_xor(se, 1);
        se += __shfl_xor(se, 2);
        float ls = mx + logf(se);
        ((float4*)out)[(size_t)node * 4 + pos] =
            make_float4(o0 - ls, o1 - ls, o2 - ls, o3 - ls);
    }
}

// ---------------------------------------------------------------------------

extern "C" void kernel_launch(void* const* d_in, const int* in_sizes, int n_in,
                              void* d_out, int out_size, void* d_ws, size_t ws_size,
                              hipStream_t stream) {
    const float* x    = (const float*)d_in[0];
    const int*   ei   = (const int*)d_in[1];
    const float* W1   = (const float*)d_in[2];
    const float* b1   = (const float*)d_in[3];
    const float* as1  = (const float*)d_in[4];
    const float* ad1  = (const float*)d_in[5];
    const float* W2   = (const float*)d_in[6];
    const float* b2   = (const float*)d_in[7];
    const float* as2  = (const float*)d_in[8];
    const float* ad2  = (const float*)d_in[9];
    float* out = (float*)d_out;

    int N = in_sizes[0] / 128;
    int E = in_sizes[1] / 2;
    const int* srcp = ei;
    const int* dstp = ei + E;
    int nbuck = (N + 511) >> 9;               // 196 for N=100k

    char* w = (char*)d_ws;
    auto alloc = [&](size_t bytes) {
        void* p = (void*)w;
        w += (bytes + 255) & ~(size_t)255;
        return p;
    };
    unsigned short* h1b = (unsigned short*)alloc((size_t)N * 64 * 2);
    float* a_s1  = (float*)alloc((size_t)N * 8 * 4);
    float* a_d1  = (float*)alloc((size_t)N * 8 * 4);
    unsigned short* heb = (unsigned short*)alloc((size_t)N * 64 * 2);
    unsigned short* h2b = (unsigned short*)alloc((size_t)N * 16 * 2);
    float* a_s2b = (float*)alloc((size_t)N * 4);
    float* a_d2b = (float*)alloc((size_t)N * 4);
    int*   rowp  = (int*)alloc((size_t)(N + 1) * 4);
    int*   srcs  = (int*)alloc((size_t)E * 4);
    int*   gcur  = (int*)alloc((size_t)nbuck * 4);
    int*   buf   = (int*)alloc((size_t)nbuck * BCAP * 4);  // 12.85 MB

    hipMemsetAsync(gcur, 0, (size_t)nbuck * 4, stream);

    int bblk = (E + ECHUNK - 1) / ECHUNK;
    bucket_kernel<<<bblk, 256, 0, stream>>>(srcp, dstp, gcur, buf, E, nbuck);
    csr_bucket_kernel<<<nbuck, 1024, 0, stream>>>(gcur, buf, rowp, srcs, N, E);

    int g1blocks = (N + 63) >> 6;
    gemm1_mfma_kernel<<<g1blocks, 256, 0, stream>>>(x, W1, as1, ad1, h1b, a_s1, a_d1, N);

    // R3: agg1 split into two half-range dispatches (diagnostic — surfaces
    // the true #2/#3 kernels in rocprof top-5; internals unchanged).
    int half = ((N / 2) + 3) & ~3;            // multiple of 4
    agg1_kernel<<<(half + 3) / 4, 256, 0, stream>>>(h1b, a_s1, a_d1, rowp, srcs, b1, heb, 0, half);
    agg1_kernel<<<((N - half) + 3) / 4, 256, 0, stream>>>(h1b, a_s1, a_d1, rowp, srcs, b1, heb, half, N);

    gemm2_kernel<<<512, 256, 0, stream>>>(heb, W2, as2, ad2, h2b, a_s2b, a_d2b, N);
    agg2_kernel<<<(N + 15) / 16, 256, 0, stream>>>(h2b, a_s2b, a_d2b, rowp, srcs, b2, out, N);
}

// Round 6
// 249.390 us; speedup vs baseline: 1.1327x; 1.0697x over previous
//
#include <hip/hip_runtime.h>
#include <hip/hip_bf16.h>

// ---------------------------------------------------------------------------
// 2-layer GAT (PyG GATConv semantics, eval mode, self-loops appended).
//   1) bucket (dst>>9, LDS-staged bucket-ordered writes -> coalesced runs)
//      R5: 512 threads, same ECHUNK (halved dependent chains, 2x waves)
//      -> csr_bucket (512-node buckets, 1024 thr + int4 sweeps, R1)
//   2) gemm1 (MFMA 16x16x32 bf16): h1 = x @ W1 -> bf16 + a_s/a_d epilogue
//   3) agg1: additive exp(v-8) agg, 16 lanes/edge ushort4 (R11 verified 59.8us)
//   4) gemm2: he @ W2 -> bf16 + a_s2/a_d2 epilogue; R5: grid 512->2048
//      (was 2 blocks/CU, 12 serial persistent iterations, latency-bound)
//   5) agg2: R4 — 4 nodes/wave, 16 lanes/node, 2-level reduction
// Lessons encoded:
//   R8  - never co-schedule scatter/atomic and MFMA personalities in one grid.
//   R10 - keep per-lane gather staging <= 8 B (ushort4), else the
//         occupancy-targeted VGPR budget serializes the gathers.
//   R12 - do NOT fuse gemm2 into agg1: any epilogue fattening (VGPR 24->28)
//         makes the allocator restructure the gather loop (3x confirmed).
//   R14 - bucket writes staged through LDS so each bucket's entries leave the
//         block as one contiguous run (~84 B) instead of 4 B random scatters.
//   R1(this session) - csr_bucket widened to 1024 thr + int4 loads (-8us).
//   R2(this session) - ECHUNK 4096->2048 REGRESSED (+4.5us: 2x gcur atomics,
//         half write runs). ECHUNK=4096; widen THREADS instead (this round).
//   R5(this session) - harness poison-fill (256MiB, 40.5us, 82% HBM peak) owns
//         the top-5 slots permanently; optimize by delta-total from here.
// ---------------------------------------------------------------------------

#define NEG_SLOPE 0.2f
#define EPS_DEN 1e-16f
#define CSHIFT 8.0f          // shift-invariant softmax; |logit| <~ 9 here
#define NBUCK_MAX 256
#define BCAP 16384
#define ECHUNK 4096          // edges per bucket block (8 per thread @ 512 thr)
#define G1_PITCH 136

typedef __attribute__((ext_vector_type(8))) short bf16x8;
typedef __attribute__((ext_vector_type(4))) float f32x4;

__device__ __forceinline__ float bf2f(unsigned short u) {
    return __uint_as_float(((unsigned)u) << 16);
}
__device__ __forceinline__ unsigned short f2bf(float f) {
    unsigned x = __float_as_uint(f);
    unsigned r = x + 0x7fffu + ((x >> 16) & 1u);
    return (unsigned short)(r >> 16);
}

// ---------------- CSR build ----------------

// bucket by dst>>9; entries staged bucket-ordered in LDS, copied out in
// per-bucket contiguous runs (avg ~21 entries = 84 B) for write coalescing.
// R5: 512 threads / 8 edges per thread (same ECHUNK -> same run lengths and
// same gcur atomic count as the verified shape; only the per-thread dependent
// LDS-atomic placement chain halves and resident waves double).
__global__ __launch_bounds__(512) void bucket_kernel(
    const int* __restrict__ src, const int* __restrict__ dst,
    int* __restrict__ gcur, int* __restrict__ buf, int E, int nbuck)
{
    __shared__ int cnt[NBUCK_MAX];       // counts -> placement cursors
    __shared__ int loff[NBUCK_MAX];      // local exclusive offsets
    __shared__ int offs[NBUCK_MAX];      // global segment base per bucket
    __shared__ int wsum[8];
    __shared__ int ldata[ECHUNK];        // packed entries, bucket-ordered
    __shared__ unsigned char bid[ECHUNK];// bucket id per slot (nbuck <= 256)
    int tid = threadIdx.x, lane = tid & 63, wv = tid >> 6;   // wv 0..7
    for (int i = tid; i < nbuck; i += 512) cnt[i] = 0;
    __syncthreads();
    int base = blockIdx.x * ECHUNK;
    int lim = min(base + ECHUNK, E);
    int dl[8];                           // ECHUNK == 512*8
#pragma unroll
    for (int k = 0; k < 8; ++k) {
        int e = base + tid + 512 * k;
        dl[k] = (e < lim) ? dst[e] : -1;
    }
#pragma unroll
    for (int k = 0; k < 8; ++k)
        if (dl[k] >= 0) atomicAdd(&cnt[dl[k] >> 9], 1);
    __syncthreads();
    // exclusive scan of counts (thread t <-> bucket t, t < nbuck <= 256)
    int c = (tid < nbuck) ? cnt[tid] : 0;
    int sc = c;
#pragma unroll
    for (int off = 1; off < 64; off <<= 1) {
        int o = __shfl_up(sc, off);
        if (lane >= off) sc += o;
    }
    if (lane == 63) wsum[wv] = sc;
    __syncthreads();
    if (tid == 0) {
        int acc = 0;
#pragma unroll
        for (int k = 0; k < 8; ++k) { int t = wsum[k]; wsum[k] = acc; acc += t; }
    }
    __syncthreads();
    if (tid < nbuck) {
        loff[tid] = wsum[wv] + sc - c;
        offs[tid] = atomicAdd(&gcur[tid], c);
        cnt[tid] = 0;                    // reuse as placement cursor
    }
    __syncthreads();
    // place entries bucket-ordered in LDS
#pragma unroll
    for (int k = 0; k < 8; ++k) {
        if (dl[k] >= 0) {
            int e = base + tid + 512 * k;
            int b = dl[k] >> 9;
            int slot = loff[b] + atomicAdd(&cnt[b], 1);
            ldata[slot] = (src[e] << 9) | (dl[k] & 511);
            bid[slot] = (unsigned char)b;
        }
    }
    __syncthreads();
    // copy out: consecutive slots in a bucket -> consecutive global dests
    int total = lim - base;
    for (int i = tid; i < total; i += 512) {
        int b = bid[i];
        int o = offs[b] + (i - loff[b]);
        if (o < BCAP) buf[(size_t)b * BCAP + o] = ldata[i];
    }
}

// per-512-node-bucket hist + scan + place.
// R1: 1024 threads (16 waves) + int4 sweeps — the 256-thr version was
// latency-bound at 196 blocks (<1 block/CU, 32 serial sweep iterations).
__global__ __launch_bounds__(1024) void csr_bucket_kernel(
    const int* __restrict__ gcur, const int* __restrict__ buf,
    int* __restrict__ rowptr, int* __restrict__ srcs, int N, int E)
{
    __shared__ int cnt[512];
    __shared__ int wsum[16];
    __shared__ int wbase[8];
    __shared__ int basesh;
    int b = blockIdx.x, tid = threadIdx.x;
    int lane = tid & 63, wv = tid >> 6;      // wv in 0..15
    if (tid < 512) cnt[tid] = 0;
    // inline prefix: base = sum_{i<b} gcur[i]  (<=196 L2-hot ints, 1 sweep)
    int part = 0;
    for (int i = tid; i < b; i += 1024) part += gcur[i];
#pragma unroll
    for (int off = 32; off >= 1; off >>= 1) part += __shfl_xor(part, off);
    if (lane == 0) wsum[wv] = part;
    __syncthreads();
    if (tid == 0) {
        int acc = 0;
#pragma unroll
        for (int k = 0; k < 16; ++k) acc += wsum[k];
        basesh = acc;
    }
    __syncthreads();
    int n = min(gcur[b], BCAP);
    const int* p = buf + (size_t)b * BCAP;
    const int4* p4 = (const int4*)p;         // 64 KiB-aligned segment
    int n4 = n >> 2;
    // phase 1: histogram (int4-vectorized, ~2 sweeps at 1024 thr)
    for (int i = tid; i < n4; i += 1024) {
        int4 v = p4[i];
        atomicAdd(&cnt[v.x & 511], 1);
        atomicAdd(&cnt[v.y & 511], 1);
        atomicAdd(&cnt[v.z & 511], 1);
        atomicAdd(&cnt[v.w & 511], 1);
    }
    for (int i = (n4 << 2) + tid; i < n; i += 1024)
        atomicAdd(&cnt[p[i] & 511], 1);
    __syncthreads();
    // scan of 512 counters on the first 8 waves (thread t <-> counter t)
    int c = (tid < 512) ? cnt[tid] : 0;
    int sc = c;
#pragma unroll
    for (int off = 1; off < 64; off <<= 1) {
        int o = __shfl_up(sc, off);
        if (lane >= off) sc += o;
    }
    if (lane == 63 && wv < 8) wsum[wv] = sc;
    __syncthreads();
    if (tid == 0) {
        int acc = 0;
#pragma unroll
        for (int k = 0; k < 8; ++k) { wbase[k] = acc; acc += wsum[k]; }
    }
    __syncthreads();
    if (tid < 512) {
        int g0 = basesh + wbase[wv] + (sc - c);   // exclusive prefix
        int node0 = (b << 9) + tid;
        if (node0 < N) rowptr[node0] = g0;
        cnt[tid] = g0;                            // placement cursor
    }
    __syncthreads();
    // phase 2: place (int4-vectorized)
    for (int i = tid; i < n4; i += 1024) {
        int4 v = p4[i];
        int px = atomicAdd(&cnt[v.x & 511], 1); srcs[px] = v.x >> 9;
        int py = atomicAdd(&cnt[v.y & 511], 1); srcs[py] = v.y >> 9;
        int pz = atomicAdd(&cnt[v.z & 511], 1); srcs[pz] = v.z >> 9;
        int pw = atomicAdd(&cnt[v.w & 511], 1); srcs[pw] = v.w >> 9;
    }
    for (int i = (n4 << 2) + tid; i < n; i += 1024) {
        int v = p[i];
        int posi = atomicAdd(&cnt[v & 511], 1);
        srcs[posi] = v >> 9;
    }
    if (b == 0 && tid == 0) rowptr[N] = E;
}

// ---------------- GEMM1 (MFMA): [N,128] @ [128,64] -> bf16 -------------------

__global__ __launch_bounds__(256) void gemm1_mfma_kernel(
    const float* __restrict__ x, const float* __restrict__ W1,
    const float* __restrict__ att_s, const float* __restrict__ att_d,
    unsigned short* __restrict__ h1b, float* __restrict__ a_s,
    float* __restrict__ a_d, int N)
{
    __shared__ unsigned short As[64 * G1_PITCH];
    __shared__ unsigned short Cs[64 * 68];
    int tid = threadIdx.x;
    int lane = tid & 63, wv = tid >> 6;
    int quad = lane >> 4, l16 = lane & 15;

    bf16x8 Bf[4][4];
#pragma unroll
    for (int ks = 0; ks < 4; ++ks)
#pragma unroll
        for (int nt = 0; nt < 4; ++nt) {
            bf16x8 f;
#pragma unroll
            for (int j = 0; j < 8; ++j)
                f[j] = (short)f2bf(W1[(ks * 32 + quad * 8 + j) * 64 + nt * 16 + l16]);
            Bf[ks][nt] = f;
        }
    float asw[4], adw[4];
#pragma unroll
    for (int nt = 0; nt < 4; ++nt) {
        asw[nt] = att_s[nt * 16 + l16];
        adw[nt] = att_d[nt * 16 + l16];
    }

    int nblocks = (N + 63) >> 6;
    for (int blk = blockIdx.x; blk < nblocks; blk += gridDim.x) {
        int row0 = blk << 6;
        __syncthreads();
#pragma unroll
        for (int i = 0; i < 8; ++i) {
            int idx = tid + 256 * i;
            int r = idx >> 5, c4 = idx & 31;
            int row = row0 + r;
            float4 v = (row < N) ? ((const float4*)x)[(size_t)row * 32 + c4]
                                 : make_float4(0.f, 0.f, 0.f, 0.f);
            ushort4 u;
            u.x = f2bf(v.x); u.y = f2bf(v.y); u.z = f2bf(v.z); u.w = f2bf(v.w);
            *(ushort4*)&As[r * G1_PITCH + c4 * 4] = u;
        }
        __syncthreads();
        f32x4 acc[4];
#pragma unroll
        for (int nt = 0; nt < 4; ++nt) acc[nt] = (f32x4){0.f, 0.f, 0.f, 0.f};
#pragma unroll
        for (int ks = 0; ks < 4; ++ks) {
            bf16x8 Af = *(const bf16x8*)&As[(wv * 16 + l16) * G1_PITCH + ks * 32 + quad * 8];
#pragma unroll
            for (int nt = 0; nt < 4; ++nt)
                acc[nt] = __builtin_amdgcn_mfma_f32_16x16x32_bf16(Af, Bf[ks][nt], acc[nt], 0, 0, 0);
        }
        int lrow = wv * 16 + quad * 4;
#pragma unroll
        for (int nt = 0; nt < 4; ++nt) {
            float ps[4], pd[4];
#pragma unroll
            for (int r = 0; r < 4; ++r) {
                ps[r] = acc[nt][r] * asw[nt];
                pd[r] = acc[nt][r] * adw[nt];
            }
#pragma unroll
            for (int off = 1; off < 8; off <<= 1)
#pragma unroll
                for (int r = 0; r < 4; ++r) {
                    ps[r] += __shfl_xor(ps[r], off);
                    pd[r] += __shfl_xor(pd[r], off);
                }
            if ((l16 & 7) == 0) {
                int head = nt * 2 + (l16 >> 3);
#pragma unroll
                for (int r = 0; r < 4; ++r) {
                    int row = row0 + lrow + r;
                    if (row < N) {
                        a_s[row * 8 + head] = ps[r];
                        a_d[row * 8 + head] = pd[r];
                    }
                }
            }
        }
#pragma unroll
        for (int nt = 0; nt < 4; ++nt)
#pragma unroll
            for (int r = 0; r < 4; ++r)
                Cs[(lrow + r) * 68 + nt * 16 + l16] = f2bf(acc[nt][r]);
        __syncthreads();
#pragma unroll
        for (int i = 0; i < 4; ++i) {
            int idx = tid + 256 * i;
            int r = idx >> 4, c4 = idx & 15;
            int row = row0 + r;
            if (row < N) {
                ushort4 u = *(const ushort4*)&Cs[r * 68 + c4 * 4];
                ((ushort4*)h1b)[(size_t)row * 16 + c4] = u;
            }
        }
    }
}

// ---------------- agg1: additive exp(v-8) agg, 16 edges in flight ------------
// q=lane>>4 edge-group (stride 4), pos=lane&15 -> channels 4pos..4pos+3,
// head hp=pos>>1. R11-verified 59.8us shape — do not fatten this kernel.
// (node0 arg retained from the R3 diagnostic; launched once with node0=0.)

__global__ __launch_bounds__(256) void agg1_kernel(
    const unsigned short* __restrict__ h1b, const float* __restrict__ a_s,
    const float* __restrict__ a_d, const int* __restrict__ rowptr,
    const int* __restrict__ srcs, const float* __restrict__ b1,
    unsigned short* __restrict__ heb, int node0, int N)
{
    int lane = threadIdx.x & 63, wid = threadIdx.x >> 6;
    int node = node0 + blockIdx.x * 4 + wid;
    if (node >= N) return;
    int q = lane >> 4, pos = lane & 15, hp = pos >> 1;
    int beg = rowptr[node], end = rowptr[node + 1];
    float adn = a_d[node * 8 + hp];
    const ushort4* h1v = (const ushort4*)h1b;    // row stride 16 ushort4

    float l = 0.f, a0 = 0.f, a1 = 0.f, a2 = 0.f, a3 = 0.f;
    if (q == 0) {                                // self-loop in group 0
        float v = a_s[node * 8 + hp] + adn;
        v = fmaxf(v, NEG_SLOPE * v);
        float p = __expf(v - CSHIFT);
        ushort4 h = h1v[(size_t)node * 16 + pos];
        l = p;
        a0 = p * bf2f(h.x); a1 = p * bf2f(h.y);
        a2 = p * bf2f(h.z); a3 = p * bf2f(h.w);
    }
    int e = beg + q;
    for (; e + 12 < end; e += 16) {
        int s0 = srcs[e], s1 = srcs[e + 4], s2 = srcs[e + 8], s3 = srcs[e + 12];
        float va0 = a_s[s0 * 8 + hp], va1 = a_s[s1 * 8 + hp];
        float va2 = a_s[s2 * 8 + hp], va3 = a_s[s3 * 8 + hp];
        ushort4 h0 = h1v[(size_t)s0 * 16 + pos];
        ushort4 h1_ = h1v[(size_t)s1 * 16 + pos];
        ushort4 h2_ = h1v[(size_t)s2 * 16 + pos];
        ushort4 h3_ = h1v[(size_t)s3 * 16 + pos];
        float v0 = va0 + adn; v0 = fmaxf(v0, NEG_SLOPE * v0);
        float v1 = va1 + adn; v1 = fmaxf(v1, NEG_SLOPE * v1);
        float v2 = va2 + adn; v2 = fmaxf(v2, NEG_SLOPE * v2);
        float v3 = va3 + adn; v3 = fmaxf(v3, NEG_SLOPE * v3);
        float p0 = __expf(v0 - CSHIFT), p1 = __expf(v1 - CSHIFT);
        float p2 = __expf(v2 - CSHIFT), p3 = __expf(v3 - CSHIFT);
        l += p0 + p1 + p2 + p3;
        a0 = fmaf(p0, bf2f(h0.x), a0); a1 = fmaf(p0, bf2f(h0.y), a1);
        a2 = fmaf(p0, bf2f(h0.z), a2); a3 = fmaf(p0, bf2f(h0.w), a3);
        a0 = fmaf(p1, bf2f(h1_.x), a0); a1 = fmaf(p1, bf2f(h1_.y), a1);
        a2 = fmaf(p1, bf2f(h1_.z), a2); a3 = fmaf(p1, bf2f(h1_.w), a3);
        a0 = fmaf(p2, bf2f(h2_.x), a0); a1 = fmaf(p2, bf2f(h2_.y), a1);
        a2 = fmaf(p2, bf2f(h2_.z), a2); a3 = fmaf(p2, bf2f(h2_.w), a3);
        a0 = fmaf(p3, bf2f(h3_.x), a0); a1 = fmaf(p3, bf2f(h3_.y), a1);
        a2 = fmaf(p3, bf2f(h3_.z), a2); a3 = fmaf(p3, bf2f(h3_.w), a3);
    }
    for (; e < end; e += 4) {
        int s = srcs[e];
        float va = a_s[s * 8 + hp];
        ushort4 h = h1v[(size_t)s * 16 + pos];
        float v = va + adn; v = fmaxf(v, NEG_SLOPE * v);
        float p = __expf(v - CSHIFT);
        l += p;
        a0 = fmaf(p, bf2f(h.x), a0); a1 = fmaf(p, bf2f(h.y), a1);
        a2 = fmaf(p, bf2f(h.z), a2); a3 = fmaf(p, bf2f(h.w), a3);
    }
#pragma unroll
    for (int off = 16; off < 64; off <<= 1) {
        l  += __shfl_xor(l, off);
        a0 += __shfl_xor(a0, off); a1 += __shfl_xor(a1, off);
        a2 += __shfl_xor(a2, off); a3 += __shfl_xor(a3, off);
    }
    if (q == 0) {
        float inv = 1.f / (l + EPS_DEN);
        float4 bb = ((const float4*)b1)[pos];
        float o0 = fmaf(a0, inv, bb.x);
        float o1 = fmaf(a1, inv, bb.y);
        float o2 = fmaf(a2, inv, bb.z);
        float o3 = fmaf(a3, inv, bb.w);
        o0 = o0 > 0.f ? o0 : __expf(o0) - 1.f;   // ELU
        o1 = o1 > 0.f ? o1 : __expf(o1) - 1.f;
        o2 = o2 > 0.f ? o2 : __expf(o2) - 1.f;
        o3 = o3 > 0.f ? o3 : __expf(o3) - 1.f;
        ushort4 u;
        u.x = f2bf(o0); u.y = f2bf(o1); u.z = f2bf(o2); u.w = f2bf(o3);
        ((ushort4*)heb)[(size_t)node * 16 + pos] = u;
    }
}

// ---------------- GEMM2: [N,64] @ [64,16] -> bf16 + a_s2/a_d2 epilogue -------
// R5: grid 512->2048 (was 2 blocks/CU with 12 serial persistent iterations of
// {stage, sync, dot} latency chains; 4x TLP, 4 iterations).

__global__ __launch_bounds__(256) void gemm2_kernel(
    const unsigned short* __restrict__ heb, const float* __restrict__ W2,
    const float* __restrict__ att_s2, const float* __restrict__ att_d2,
    unsigned short* __restrict__ h2b, float* __restrict__ a_s2,
    float* __restrict__ a_d2, int N)
{
    __shared__ float xs[4][4 * 68];
    int lane = threadIdx.x & 63, wid = threadIdx.x >> 6;
    int sub = lane >> 4, c = lane & 15;
    float wcol[64];
#pragma unroll
    for (int k = 0; k < 64; ++k) wcol[k] = W2[k * 16 + c];
    float asw = att_s2[c], adw = att_d2[c];
    int groups = (N + 15) >> 4;
    int iters = (groups + gridDim.x - 1) / gridDim.x;
    for (int it = 0; it < iters; ++it) {
        int g = blockIdx.x + it * gridDim.x;
        int nb = g * 16 + wid * 4;
        __syncthreads();
        if (g < groups) {
#pragma unroll
            for (int i = 0; i < 4; ++i) {
                int n = nb + i;
                xs[wid][i * 68 + lane] = (n < N) ? bf2f(heb[(size_t)n * 64 + lane]) : 0.f;
            }
        }
        __syncthreads();
        if (g < groups) {
            int node = nb + sub;
            const float4* xv = (const float4*)&xs[wid][sub * 68];
            float acc = 0.f;
#pragma unroll
            for (int k4 = 0; k4 < 16; ++k4) {
                float4 v = xv[k4];
                acc += v.x * wcol[4 * k4 + 0] + v.y * wcol[4 * k4 + 1]
                     + v.z * wcol[4 * k4 + 2] + v.w * wcol[4 * k4 + 3];
            }
            if (node < N) {
                h2b[(size_t)node * 16 + c] = f2bf(acc);
                float rs = acc * asw, rd = acc * adw;
#pragma unroll
                for (int off = 1; off < 16; off <<= 1) {
                    rs += __shfl_xor(rs, off);
                    rd += __shfl_xor(rd, off);
                }
                if (c == 0) { a_s2[node] = rs; a_d2[node] = rd; }
            }
        }
    }
}

// ---------------- agg2: additive exp(v-8) agg + fused log_softmax ------------
// R4: 4 nodes/wave, 16 lanes/node. nsub=lane>>4 node, q=(lane>>2)&3 edge-group
// (stride 4), pos=lane&3 -> classes 4pos..4pos+3. 2-level shfl reduction
// (off 4,8) amortized over 4 nodes; deg~17/4 groups pipelines ~4 gathers/lane.

__global__ __launch_bounds__(256) void agg2_kernel(
    const unsigned short* __restrict__ h2b, const float* __restrict__ a_s2,
    const float* __restrict__ a_d2, const int* __restrict__ rowptr,
    const int* __restrict__ srcs, const float* __restrict__ b2,
    float* __restrict__ out, int N)
{
    int lane = threadIdx.x & 63, wid = threadIdx.x >> 6;
    int nsub = lane >> 4;
    int node = blockIdx.x * 16 + wid * 4 + nsub;
    if (node >= N) return;
    int q = (lane >> 2) & 3, pos = lane & 3;
    int beg = rowptr[node], end = rowptr[node + 1];
    float adn = a_d2[node];
    const ushort4* h2v = (const ushort4*)h2b;    // row stride 4 ushort4

    float l = 0.f, a0 = 0.f, a1 = 0.f, a2 = 0.f, a3 = 0.f;
    if (q == 0) {                                // self-loop in group 0
        float v = a_s2[node] + adn;
        v = fmaxf(v, NEG_SLOPE * v);
        float p = __expf(v - CSHIFT);
        ushort4 h = h2v[(size_t)node * 4 + pos];
        l = p;
        a0 = p * bf2f(h.x); a1 = p * bf2f(h.y);
        a2 = p * bf2f(h.z); a3 = p * bf2f(h.w);
    }
    int e = beg + q;
    for (; e + 4 < end; e += 8) {
        int s0 = srcs[e], s1 = srcs[e + 4];
        float va0 = a_s2[s0], va1 = a_s2[s1];
        ushort4 h0 = h2v[(size_t)s0 * 4 + pos];
        ushort4 h1_ = h2v[(size_t)s1 * 4 + pos];
        float v0 = va0 + adn; v0 = fmaxf(v0, NEG_SLOPE * v0);
        float v1 = va1 + adn; v1 = fmaxf(v1, NEG_SLOPE * v1);
        float p0 = __expf(v0 - CSHIFT), p1 = __expf(v1 - CSHIFT);
        l += p0 + p1;
        a0 = fmaf(p0, bf2f(h0.x), a0); a1 = fmaf(p0, bf2f(h0.y), a1);
        a2 = fmaf(p0, bf2f(h0.z), a2); a3 = fmaf(p0, bf2f(h0.w), a3);
        a0 = fmaf(p1, bf2f(h1_.x), a0); a1 = fmaf(p1, bf2f(h1_.y), a1);
        a2 = fmaf(p1, bf2f(h1_.z), a2); a3 = fmaf(p1, bf2f(h1_.w), a3);
    }
    for (; e < end; e += 4) {
        int s = srcs[e];
        float va = a_s2[s];
        ushort4 h = h2v[(size_t)s * 4 + pos];
        float v = va + adn; v = fmaxf(v, NEG_SLOPE * v);
        float p = __expf(v - CSHIFT);
        l += p;
        a0 = fmaf(p, bf2f(h.x), a0); a1 = fmaf(p, bf2f(h.y), a1);
        a2 = fmaf(p, bf2f(h.z), a2); a3 = fmaf(p, bf2f(h.w), a3);
    }
#pragma unroll
    for (int off = 4; off < 16; off <<= 1) {
        l  += __shfl_xor(l, off);
        a0 += __shfl_xor(a0, off); a1 += __shfl_xor(a1, off);
        a2 += __shfl_xor(a2, off); a3 += __shfl_xor(a3, off);
    }
    if (q == 0) {
        float inv = 1.f / (l + EPS_DEN);
        float4 bb = ((const float4*)b2)[pos];
        float o0 = fmaf(a0, inv, bb.x);
        float o1 = fmaf(a1, inv, bb.y);
        float o2 = fmaf(a2, inv, bb.z);
        float o3 = fmaf(a3, inv, bb.w);
        float mx = fmaxf(fmaxf(o0, o1), fmaxf(o2, o3));
        mx = fmaxf(mx, __shfl_xor(mx, 1));
        mx = fmaxf(mx, __shfl_xor(mx, 2));
        float se = __expf(o0 - mx) + __expf(o1 - mx)
                 + __expf(o2 - mx) + __expf(o3 - mx);
        se += __shfl_xor(se, 1);
        se += __shfl_xor(se, 2);
        float ls = mx + logf(se);
        ((float4*)out)[(size_t)node * 4 + pos] =
            make_float4(o0 - ls, o1 - ls, o2 - ls, o3 - ls);
    }
}

// ---------------------------------------------------------------------------

extern "C" void kernel_launch(void* const* d_in, const int* in_sizes, int n_in,
                              void* d_out, int out_size, void* d_ws, size_t ws_size,
                              hipStream_t stream) {
    const float* x    = (const float*)d_in[0];
    const int*   ei   = (const int*)d_in[1];
    const float* W1   = (const float*)d_in[2];
    const float* b1   = (const float*)d_in[3];
    const float* as1  = (const float*)d_in[4];
    const float* ad1  = (const float*)d_in[5];
    const float* W2   = (const float*)d_in[6];
    const float* b2   = (const float*)d_in[7];
    const float* as2  = (const float*)d_in[8];
    const float* ad2  = (const float*)d_in[9];
    float* out = (float*)d_out;

    int N = in_sizes[0] / 128;
    int E = in_sizes[1] / 2;
    const int* srcp = ei;
    const int* dstp = ei + E;
    int nbuck = (N + 511) >> 9;               // 196 for N=100k

    char* w = (char*)d_ws;
    auto alloc = [&](size_t bytes) {
        void* p = (void*)w;
        w += (bytes + 255) & ~(size_t)255;
        return p;
    };
    unsigned short* h1b = (unsigned short*)alloc((size_t)N * 64 * 2);
    float* a_s1  = (float*)alloc((size_t)N * 8 * 4);
    float* a_d1  = (float*)alloc((size_t)N * 8 * 4);
    unsigned short* heb = (unsigned short*)alloc((size_t)N * 64 * 2);
    unsigned short* h2b = (unsigned short*)alloc((size_t)N * 16 * 2);
    float* a_s2b = (float*)alloc((size_t)N * 4);
    float* a_d2b = (float*)alloc((size_t)N * 4);
    int*   rowp  = (int*)alloc((size_t)(N + 1) * 4);
    int*   srcs  = (int*)alloc((size_t)E * 4);
    int*   gcur  = (int*)alloc((size_t)nbuck * 4);
    int*   buf   = (int*)alloc((size_t)nbuck * BCAP * 4);  // 12.85 MB

    hipMemsetAsync(gcur, 0, (size_t)nbuck * 4, stream);

    int bblk = (E + ECHUNK - 1) / ECHUNK;
    bucket_kernel<<<bblk, 512, 0, stream>>>(srcp, dstp, gcur, buf, E, nbuck);
    csr_bucket_kernel<<<nbuck, 1024, 0, stream>>>(gcur, buf, rowp, srcs, N, E);

    int g1blocks = (N + 63) >> 6;
    gemm1_mfma_kernel<<<g1blocks, 256, 0, stream>>>(x, W1, as1, ad1, h1b, a_s1, a_d1, N);
    agg1_kernel<<<(N + 3) / 4, 256, 0, stream>>>(h1b, a_s1, a_d1, rowp, srcs, b1, heb, 0, N);
    gemm2_kernel<<<2048, 256, 0, stream>>>(heb, W2, as2, ad2, h2b, a_s2b, a_d2b, N);
    agg2_kernel<<<(N + 15) / 16, 256, 0, stream>>>(h2b, a_s2b, a_d2b, rowp, srcs, b2, out, N);
}

// Round 7
// 249.066 us; speedup vs baseline: 1.1341x; 1.0013x over previous
//
#include <hip/hip_runtime.h>
#include <hip/hip_bf16.h>

// ---------------------------------------------------------------------------
// 2-layer GAT (PyG GATConv semantics, eval mode, self-loops appended).
//   1) bucket (dst>>9, LDS-staged bucket-ordered writes -> coalesced runs)
//      R5: 512 thr; R6: 1024 thr, same ECHUNK (chains 4-deep, 2x waves again)
//      -> csr_bucket (512-node buckets, 1024 thr + int4 sweeps, R1)
//   2) gemm1 (MFMA 16x16x32 bf16): h1 = x @ W1 -> bf16 + a_s/a_d epilogue
//   3) agg1: additive exp(v-8) agg, 16 lanes/edge ushort4 (R11 verified 59.8us)
//   4) gemm2: he @ W2 -> bf16 + a_s2/a_d2 epilogue; R5: grid 512->2048
//   5) agg2: R4 — 4 nodes/wave, 16 lanes/node, 2-level reduction
// Lessons encoded:
//   R8  - never co-schedule scatter/atomic and MFMA personalities in one grid.
//   R10 - keep per-lane gather staging <= 8 B (ushort4), else the
//         occupancy-targeted VGPR budget serializes the gathers.
//   R12 - do NOT fuse gemm2 into agg1: any epilogue fattening (VGPR 24->28)
//         makes the allocator restructure the gather loop (3x confirmed).
//   R14 - bucket writes staged through LDS so each bucket's entries leave the
//         block as one contiguous run (~84 B) instead of 4 B random scatters.
//   R1(this session) - csr_bucket widened to 1024 thr + int4 loads (-8us).
//   R2(this session) - ECHUNK 4096->2048 REGRESSED (+4.5us: 2x gcur atomics,
//         half write runs). ECHUNK=4096; widen THREADS instead (R5: -17.4us
//         together with gemm2 grid 2048).
//   R5(this session) - harness poison-fill (256MiB, 40.5us, 82% HBM peak) owns
//         the top-5 slots permanently; optimize by delta-total from here.
// ---------------------------------------------------------------------------

#define NEG_SLOPE 0.2f
#define EPS_DEN 1e-16f
#define CSHIFT 8.0f          // shift-invariant softmax; |logit| <~ 9 here
#define NBUCK_MAX 256
#define BCAP 16384
#define ECHUNK 4096          // edges per bucket block (4 per thread @ 1024 thr)
#define G1_PITCH 136

typedef __attribute__((ext_vector_type(8))) short bf16x8;
typedef __attribute__((ext_vector_type(4))) float f32x4;

__device__ __forceinline__ float bf2f(unsigned short u) {
    return __uint_as_float(((unsigned)u) << 16);
}
__device__ __forceinline__ unsigned short f2bf(float f) {
    unsigned x = __float_as_uint(f);
    unsigned r = x + 0x7fffu + ((x >> 16) & 1u);
    return (unsigned short)(r >> 16);
}

// ---------------- CSR build ----------------

// bucket by dst>>9; entries staged bucket-ordered in LDS, copied out in
// per-bucket contiguous runs (avg ~21 entries = 84 B) for write coalescing.
// R6: 1024 threads / 4 edges per thread (same ECHUNK -> same run lengths and
// same gcur atomic count; per-thread dependent LDS-atomic chain now 4-deep).
__global__ __launch_bounds__(1024) void bucket_kernel(
    const int* __restrict__ src, const int* __restrict__ dst,
    int* __restrict__ gcur, int* __restrict__ buf, int E, int nbuck)
{
    __shared__ int cnt[NBUCK_MAX];       // counts -> placement cursors
    __shared__ int loff[NBUCK_MAX];      // local exclusive offsets
    __shared__ int offs[NBUCK_MAX];      // global segment base per bucket
    __shared__ int wsum[16];
    __shared__ int ldata[ECHUNK];        // packed entries, bucket-ordered
    __shared__ unsigned char bid[ECHUNK];// bucket id per slot (nbuck <= 256)
    int tid = threadIdx.x, lane = tid & 63, wv = tid >> 6;   // wv 0..15
    for (int i = tid; i < nbuck; i += 1024) cnt[i] = 0;
    __syncthreads();
    int base = blockIdx.x * ECHUNK;
    int lim = min(base + ECHUNK, E);
    int dl[4];                           // ECHUNK == 1024*4
#pragma unroll
    for (int k = 0; k < 4; ++k) {
        int e = base + tid + 1024 * k;
        dl[k] = (e < lim) ? dst[e] : -1;
    }
#pragma unroll
    for (int k = 0; k < 4; ++k)
        if (dl[k] >= 0) atomicAdd(&cnt[dl[k] >> 9], 1);
    __syncthreads();
    // exclusive scan of counts (thread t <-> bucket t, t < nbuck <= 256;
    // waves >= 4 contribute zeros)
    int c = (tid < nbuck) ? cnt[tid] : 0;
    int sc = c;
#pragma unroll
    for (int off = 1; off < 64; off <<= 1) {
        int o = __shfl_up(sc, off);
        if (lane >= off) sc += o;
    }
    if (lane == 63) wsum[wv] = sc;
    __syncthreads();
    if (tid == 0) {
        int acc = 0;
#pragma unroll
        for (int k = 0; k < 16; ++k) { int t = wsum[k]; wsum[k] = acc; acc += t; }
    }
    __syncthreads();
    if (tid < nbuck) {
        loff[tid] = wsum[wv] + sc - c;
        offs[tid] = atomicAdd(&gcur[tid], c);
        cnt[tid] = 0;                    // reuse as placement cursor
    }
    __syncthreads();
    // place entries bucket-ordered in LDS
#pragma unroll
    for (int k = 0; k < 4; ++k) {
        if (dl[k] >= 0) {
            int e = base + tid + 1024 * k;
            int b = dl[k] >> 9;
            int slot = loff[b] + atomicAdd(&cnt[b], 1);
            ldata[slot] = (src[e] << 9) | (dl[k] & 511);
            bid[slot] = (unsigned char)b;
        }
    }
    __syncthreads();
    // copy out: consecutive slots in a bucket -> consecutive global dests
    int total = lim - base;
    for (int i = tid; i < total; i += 1024) {
        int b = bid[i];
        int o = offs[b] + (i - loff[b]);
        if (o < BCAP) buf[(size_t)b * BCAP + o] = ldata[i];
    }
}

// per-512-node-bucket hist + scan + place.
// R1: 1024 threads (16 waves) + int4 sweeps — the 256-thr version was
// latency-bound at 196 blocks (<1 block/CU, 32 serial sweep iterations).
__global__ __launch_bounds__(1024) void csr_bucket_kernel(
    const int* __restrict__ gcur, const int* __restrict__ buf,
    int* __restrict__ rowptr, int* __restrict__ srcs, int N, int E)
{
    __shared__ int cnt[512];
    __shared__ int wsum[16];
    __shared__ int wbase[8];
    __shared__ int basesh;
    int b = blockIdx.x, tid = threadIdx.x;
    int lane = tid & 63, wv = tid >> 6;      // wv in 0..15
    if (tid < 512) cnt[tid] = 0;
    // inline prefix: base = sum_{i<b} gcur[i]  (<=196 L2-hot ints, 1 sweep)
    int part = 0;
    for (int i = tid; i < b; i += 1024) part += gcur[i];
#pragma unroll
    for (int off = 32; off >= 1; off >>= 1) part += __shfl_xor(part, off);
    if (lane == 0) wsum[wv] = part;
    __syncthreads();
    if (tid == 0) {
        int acc = 0;
#pragma unroll
        for (int k = 0; k < 16; ++k) acc += wsum[k];
        basesh = acc;
    }
    __syncthreads();
    int n = min(gcur[b], BCAP);
    const int* p = buf + (size_t)b * BCAP;
    const int4* p4 = (const int4*)p;         // 64 KiB-aligned segment
    int n4 = n >> 2;
    // phase 1: histogram (int4-vectorized, ~2 sweeps at 1024 thr)
    for (int i = tid; i < n4; i += 1024) {
        int4 v = p4[i];
        atomicAdd(&cnt[v.x & 511], 1);
        atomicAdd(&cnt[v.y & 511], 1);
        atomicAdd(&cnt[v.z & 511], 1);
        atomicAdd(&cnt[v.w & 511], 1);
    }
    for (int i = (n4 << 2) + tid; i < n; i += 1024)
        atomicAdd(&cnt[p[i] & 511], 1);
    __syncthreads();
    // scan of 512 counters on the first 8 waves (thread t <-> counter t)
    int c = (tid < 512) ? cnt[tid] : 0;
    int sc = c;
#pragma unroll
    for (int off = 1; off < 64; off <<= 1) {
        int o = __shfl_up(sc, off);
        if (lane >= off) sc += o;
    }
    if (lane == 63 && wv < 8) wsum[wv] = sc;
    __syncthreads();
    if (tid == 0) {
        int acc = 0;
#pragma unroll
        for (int k = 0; k < 8; ++k) { wbase[k] = acc; acc += wsum[k]; }
    }
    __syncthreads();
    if (tid < 512) {
        int g0 = basesh + wbase[wv] + (sc - c);   // exclusive prefix
        int node0 = (b << 9) + tid;
        if (node0 < N) rowptr[node0] = g0;
        cnt[tid] = g0;                            // placement cursor
    }
    __syncthreads();
    // phase 2: place (int4-vectorized)
    for (int i = tid; i < n4; i += 1024) {
        int4 v = p4[i];
        int px = atomicAdd(&cnt[v.x & 511], 1); srcs[px] = v.x >> 9;
        int py = atomicAdd(&cnt[v.y & 511], 1); srcs[py] = v.y >> 9;
        int pz = atomicAdd(&cnt[v.z & 511], 1); srcs[pz] = v.z >> 9;
        int pw = atomicAdd(&cnt[v.w & 511], 1); srcs[pw] = v.w >> 9;
    }
    for (int i = (n4 << 2) + tid; i < n; i += 1024) {
        int v = p[i];
        int posi = atomicAdd(&cnt[v & 511], 1);
        srcs[posi] = v >> 9;
    }
    if (b == 0 && tid == 0) rowptr[N] = E;
}

// ---------------- GEMM1 (MFMA): [N,128] @ [128,64] -> bf16 -------------------

__global__ __launch_bounds__(256) void gemm1_mfma_kernel(
    const float* __restrict__ x, const float* __restrict__ W1,
    const float* __restrict__ att_s, const float* __restrict__ att_d,
    unsigned short* __restrict__ h1b, float* __restrict__ a_s,
    float* __restrict__ a_d, int N)
{
    __shared__ unsigned short As[64 * G1_PITCH];
    __shared__ unsigned short Cs[64 * 68];
    int tid = threadIdx.x;
    int lane = tid & 63, wv = tid >> 6;
    int quad = lane >> 4, l16 = lane & 15;

    bf16x8 Bf[4][4];
#pragma unroll
    for (int ks = 0; ks < 4; ++ks)
#pragma unroll
        for (int nt = 0; nt < 4; ++nt) {
            bf16x8 f;
#pragma unroll
            for (int j = 0; j < 8; ++j)
                f[j] = (short)f2bf(W1[(ks * 32 + quad * 8 + j) * 64 + nt * 16 + l16]);
            Bf[ks][nt] = f;
        }
    float asw[4], adw[4];
#pragma unroll
    for (int nt = 0; nt < 4; ++nt) {
        asw[nt] = att_s[nt * 16 + l16];
        adw[nt] = att_d[nt * 16 + l16];
    }

    int nblocks = (N + 63) >> 6;
    for (int blk = blockIdx.x; blk < nblocks; blk += gridDim.x) {
        int row0 = blk << 6;
        __syncthreads();
#pragma unroll
        for (int i = 0; i < 8; ++i) {
            int idx = tid + 256 * i;
            int r = idx >> 5, c4 = idx & 31;
            int row = row0 + r;
            float4 v = (row < N) ? ((const float4*)x)[(size_t)row * 32 + c4]
                                 : make_float4(0.f, 0.f, 0.f, 0.f);
            ushort4 u;
            u.x = f2bf(v.x); u.y = f2bf(v.y); u.z = f2bf(v.z); u.w = f2bf(v.w);
            *(ushort4*)&As[r * G1_PITCH + c4 * 4] = u;
        }
        __syncthreads();
        f32x4 acc[4];
#pragma unroll
        for (int nt = 0; nt < 4; ++nt) acc[nt] = (f32x4){0.f, 0.f, 0.f, 0.f};
#pragma unroll
        for (int ks = 0; ks < 4; ++ks) {
            bf16x8 Af = *(const bf16x8*)&As[(wv * 16 + l16) * G1_PITCH + ks * 32 + quad * 8];
#pragma unroll
            for (int nt = 0; nt < 4; ++nt)
                acc[nt] = __builtin_amdgcn_mfma_f32_16x16x32_bf16(Af, Bf[ks][nt], acc[nt], 0, 0, 0);
        }
        int lrow = wv * 16 + quad * 4;
#pragma unroll
        for (int nt = 0; nt < 4; ++nt) {
            float ps[4], pd[4];
#pragma unroll
            for (int r = 0; r < 4; ++r) {
                ps[r] = acc[nt][r] * asw[nt];
                pd[r] = acc[nt][r] * adw[nt];
            }
#pragma unroll
            for (int off = 1; off < 8; off <<= 1)
#pragma unroll
                for (int r = 0; r < 4; ++r) {
                    ps[r] += __shfl_xor(ps[r], off);
                    pd[r] += __shfl_xor(pd[r], off);
                }
            if ((l16 & 7) == 0) {
                int head = nt * 2 + (l16 >> 3);
#pragma unroll
                for (int r = 0; r < 4; ++r) {
                    int row = row0 + lrow + r;
                    if (row < N) {
                        a_s[row * 8 + head] = ps[r];
                        a_d[row * 8 + head] = pd[r];
                    }
                }
            }
        }
#pragma unroll
        for (int nt = 0; nt < 4; ++nt)
#pragma unroll
            for (int r = 0; r < 4; ++r)
                Cs[(lrow + r) * 68 + nt * 16 + l16] = f2bf(acc[nt][r]);
        __syncthreads();
#pragma unroll
        for (int i = 0; i < 4; ++i) {
            int idx = tid + 256 * i;
            int r = idx >> 4, c4 = idx & 15;
            int row = row0 + r;
            if (row < N) {
                ushort4 u = *(const ushort4*)&Cs[r * 68 + c4 * 4];
                ((ushort4*)h1b)[(size_t)row * 16 + c4] = u;
            }
        }
    }
}

// ---------------- agg1: additive exp(v-8) agg, 16 edges in flight ------------
// q=lane>>4 edge-group (stride 4), pos=lane&15 -> channels 4pos..4pos+3,
// head hp=pos>>1. R11-verified 59.8us shape — do not fatten this kernel.

__global__ __launch_bounds__(256) void agg1_kernel(
    const unsigned short* __restrict__ h1b, const float* __restrict__ a_s,
    const float* __restrict__ a_d, const int* __restrict__ rowptr,
    const int* __restrict__ srcs, const float* __restrict__ b1,
    unsigned short* __restrict__ heb, int node0, int N)
{
    int lane = threadIdx.x & 63, wid = threadIdx.x >> 6;
    int node = node0 + blockIdx.x * 4 + wid;
    if (node >= N) return;
    int q = lane >> 4, pos = lane & 15, hp = pos >> 1;
    int beg = rowptr[node], end = rowptr[node + 1];
    float adn = a_d[node * 8 + hp];
    const ushort4* h1v = (const ushort4*)h1b;    // row stride 16 ushort4

    float l = 0.f, a0 = 0.f, a1 = 0.f, a2 = 0.f, a3 = 0.f;
    if (q == 0) {                                // self-loop in group 0
        float v = a_s[node * 8 + hp] + adn;
        v = fmaxf(v, NEG_SLOPE * v);
        float p = __expf(v - CSHIFT);
        ushort4 h = h1v[(size_t)node * 16 + pos];
        l = p;
        a0 = p * bf2f(h.x); a1 = p * bf2f(h.y);
        a2 = p * bf2f(h.z); a3 = p * bf2f(h.w);
    }
    int e = beg + q;
    for (; e + 12 < end; e += 16) {
        int s0 = srcs[e], s1 = srcs[e + 4], s2 = srcs[e + 8], s3 = srcs[e + 12];
        float va0 = a_s[s0 * 8 + hp], va1 = a_s[s1 * 8 + hp];
        float va2 = a_s[s2 * 8 + hp], va3 = a_s[s3 * 8 + hp];
        ushort4 h0 = h1v[(size_t)s0 * 16 + pos];
        ushort4 h1_ = h1v[(size_t)s1 * 16 + pos];
        ushort4 h2_ = h1v[(size_t)s2 * 16 + pos];
        ushort4 h3_ = h1v[(size_t)s3 * 16 + pos];
        float v0 = va0 + adn; v0 = fmaxf(v0, NEG_SLOPE * v0);
        float v1 = va1 + adn; v1 = fmaxf(v1, NEG_SLOPE * v1);
        float v2 = va2 + adn; v2 = fmaxf(v2, NEG_SLOPE * v2);
        float v3 = va3 + adn; v3 = fmaxf(v3, NEG_SLOPE * v3);
        float p0 = __expf(v0 - CSHIFT), p1 = __expf(v1 - CSHIFT);
        float p2 = __expf(v2 - CSHIFT), p3 = __expf(v3 - CSHIFT);
        l += p0 + p1 + p2 + p3;
        a0 = fmaf(p0, bf2f(h0.x), a0); a1 = fmaf(p0, bf2f(h0.y), a1);
        a2 = fmaf(p0, bf2f(h0.z), a2); a3 = fmaf(p0, bf2f(h0.w), a3);
        a0 = fmaf(p1, bf2f(h1_.x), a0); a1 = fmaf(p1, bf2f(h1_.y), a1);
        a2 = fmaf(p1, bf2f(h1_.z), a2); a3 = fmaf(p1, bf2f(h1_.w), a3);
        a0 = fmaf(p2, bf2f(h2_.x), a0); a1 = fmaf(p2, bf2f(h2_.y), a1);
        a2 = fmaf(p2, bf2f(h2_.z), a2); a3 = fmaf(p2, bf2f(h2_.w), a3);
        a0 = fmaf(p3, bf2f(h3_.x), a0); a1 = fmaf(p3, bf2f(h3_.y), a1);
        a2 = fmaf(p3, bf2f(h3_.z), a2); a3 = fmaf(p3, bf2f(h3_.w), a3);
    }
    for (; e < end; e += 4) {
        int s = srcs[e];
        float va = a_s[s * 8 + hp];
        ushort4 h = h1v[(size_t)s * 16 + pos];
        float v = va + adn; v = fmaxf(v, NEG_SLOPE * v);
        float p = __expf(v - CSHIFT);
        l += p;
        a0 = fmaf(p, bf2f(h.x), a0); a1 = fmaf(p, bf2f(h.y), a1);
        a2 = fmaf(p, bf2f(h.z), a2); a3 = fmaf(p, bf2f(h.w), a3);
    }
#pragma unroll
    for (int off = 16; off < 64; off <<= 1) {
        l  += __shfl_xor(l, off);
        a0 += __shfl_xor(a0, off); a1 += __shfl_xor(a1, off);
        a2 += __shfl_xor(a2, off); a3 += __shfl_xor(a3, off);
    }
    if (q == 0) {
        float inv = 1.f / (l + EPS_DEN);
        float4 bb = ((const float4*)b1)[pos];
        float o0 = fmaf(a0, inv, bb.x);
        float o1 = fmaf(a1, inv, bb.y);
        float o2 = fmaf(a2, inv, bb.z);
        float o3 = fmaf(a3, inv, bb.w);
        o0 = o0 > 0.f ? o0 : __expf(o0) - 1.f;   // ELU
        o1 = o1 > 0.f ? o1 : __expf(o1) - 1.f;
        o2 = o2 > 0.f ? o2 : __expf(o2) - 1.f;
        o3 = o3 > 0.f ? o3 : __expf(o3) - 1.f;
        ushort4 u;
        u.x = f2bf(o0); u.y = f2bf(o1); u.z = f2bf(o2); u.w = f2bf(o3);
        ((ushort4*)heb)[(size_t)node * 16 + pos] = u;
    }
}

// ---------------- GEMM2: [N,64] @ [64,16] -> bf16 + a_s2/a_d2 epilogue -------
// R5: grid 512->2048 (was 2 blocks/CU with 12 serial persistent iterations of
// {stage, sync, dot} latency chains; 4x TLP, 4 iterations).

__global__ __launch_bounds__(256) void gemm2_kernel(
    const unsigned short* __restrict__ heb, const float* __restrict__ W2,
    const float* __restrict__ att_s2, const float* __restrict__ att_d2,
    unsigned short* __restrict__ h2b, float* __restrict__ a_s2,
    float* __restrict__ a_d2, int N)
{
    __shared__ float xs[4][4 * 68];
    int lane = threadIdx.x & 63, wid = threadIdx.x >> 6;
    int sub = lane >> 4, c = lane & 15;
    float wcol[64];
#pragma unroll
    for (int k = 0; k < 64; ++k) wcol[k] = W2[k * 16 + c];
    float asw = att_s2[c], adw = att_d2[c];
    int groups = (N + 15) >> 4;
    int iters = (groups + gridDim.x - 1) / gridDim.x;
    for (int it = 0; it < iters; ++it) {
        int g = blockIdx.x + it * gridDim.x;
        int nb = g * 16 + wid * 4;
        __syncthreads();
        if (g < groups) {
#pragma unroll
            for (int i = 0; i < 4; ++i) {
                int n = nb + i;
                xs[wid][i * 68 + lane] = (n < N) ? bf2f(heb[(size_t)n * 64 + lane]) : 0.f;
            }
        }
        __syncthreads();
        if (g < groups) {
            int node = nb + sub;
            const float4* xv = (const float4*)&xs[wid][sub * 68];
            float acc = 0.f;
#pragma unroll
            for (int k4 = 0; k4 < 16; ++k4) {
                float4 v = xv[k4];
                acc += v.x * wcol[4 * k4 + 0] + v.y * wcol[4 * k4 + 1]
                     + v.z * wcol[4 * k4 + 2] + v.w * wcol[4 * k4 + 3];
            }
            if (node < N) {
                h2b[(size_t)node * 16 + c] = f2bf(acc);
                float rs = acc * asw, rd = acc * adw;
#pragma unroll
                for (int off = 1; off < 16; off <<= 1) {
                    rs += __shfl_xor(rs, off);
                    rd += __shfl_xor(rd, off);
                }
                if (c == 0) { a_s2[node] = rs; a_d2[node] = rd; }
            }
        }
    }
}

// ---------------- agg2: additive exp(v-8) agg + fused log_softmax ------------
// R4: 4 nodes/wave, 16 lanes/node. nsub=lane>>4 node, q=(lane>>2)&3 edge-group
// (stride 4), pos=lane&3 -> classes 4pos..4pos+3. 2-level shfl reduction
// (off 4,8) amortized over 4 nodes; deg~17/4 groups pipelines ~4 gathers/lane.

__global__ __launch_bounds__(256) void agg2_kernel(
    const unsigned short* __restrict__ h2b, const float* __restrict__ a_s2,
    const float* __restrict__ a_d2, const int* __restrict__ rowptr,
    const int* __restrict__ srcs, const float* __restrict__ b2,
    float* __restrict__ out, int N)
{
    int lane = threadIdx.x & 63, wid = threadIdx.x >> 6;
    int nsub = lane >> 4;
    int node = blockIdx.x * 16 + wid * 4 + nsub;
    if (node >= N) return;
    int q = (lane >> 2) & 3, pos = lane & 3;
    int beg = rowptr[node], end = rowptr[node + 1];
    float adn = a_d2[node];
    const ushort4* h2v = (const ushort4*)h2b;    // row stride 4 ushort4

    float l = 0.f, a0 = 0.f, a1 = 0.f, a2 = 0.f, a3 = 0.f;
    if (q == 0) {                                // self-loop in group 0
        float v = a_s2[node] + adn;
        v = fmaxf(v, NEG_SLOPE * v);
        float p = __expf(v - CSHIFT);
        ushort4 h = h2v[(size_t)node * 4 + pos];
        l = p;
        a0 = p * bf2f(h.x); a1 = p * bf2f(h.y);
        a2 = p * bf2f(h.z); a3 = p * bf2f(h.w);
    }
    int e = beg + q;
    for (; e + 4 < end; e += 8) {
        int s0 = srcs[e], s1 = srcs[e + 4];
        float va0 = a_s2[s0], va1 = a_s2[s1];
        ushort4 h0 = h2v[(size_t)s0 * 4 + pos];
        ushort4 h1_ = h2v[(size_t)s1 * 4 + pos];
        float v0 = va0 + adn; v0 = fmaxf(v0, NEG_SLOPE * v0);
        float v1 = va1 + adn; v1 = fmaxf(v1, NEG_SLOPE * v1);
        float p0 = __expf(v0 - CSHIFT), p1 = __expf(v1 - CSHIFT);
        l += p0 + p1;
        a0 = fmaf(p0, bf2f(h0.x), a0); a1 = fmaf(p0, bf2f(h0.y), a1);
        a2 = fmaf(p0, bf2f(h0.z), a2); a3 = fmaf(p0, bf2f(h0.w), a3);
        a0 = fmaf(p1, bf2f(h1_.x), a0); a1 = fmaf(p1, bf2f(h1_.y), a1);
        a2 = fmaf(p1, bf2f(h1_.z), a2); a3 = fmaf(p1, bf2f(h1_.w), a3);
    }
    for (; e < end; e += 4) {
        int s = srcs[e];
        float va = a_s2[s];
        ushort4 h = h2v[(size_t)s * 4 + pos];
        float v = va + adn; v = fmaxf(v, NEG_SLOPE * v);
        float p = __expf(v - CSHIFT);
        l += p;
        a0 = fmaf(p, bf2f(h.x), a0); a1 = fmaf(p, bf2f(h.y), a1);
        a2 = fmaf(p, bf2f(h.z), a2); a3 = fmaf(p, bf2f(h.w), a3);
    }
#pragma unroll
    for (int off = 4; off < 16; off <<= 1) {
        l  += __shfl_xor(l, off);
        a0 += __shfl_xor(a0, off); a1 += __shfl_xor(a1, off);
        a2 += __shfl_xor(a2, off); a3 += __shfl_xor(a3, off);
    }
    if (q == 0) {
        float inv = 1.f / (l + EPS_DEN);
        float4 bb = ((const float4*)b2)[pos];
        float o0 = fmaf(a0, inv, bb.x);
        float o1 = fmaf(a1, inv, bb.y);
        float o2 = fmaf(a2, inv, bb.z);
        float o3 = fmaf(a3, inv, bb.w);
        float mx = fmaxf(fmaxf(o0, o1), fmaxf(o2, o3));
        mx = fmaxf(mx, __shfl_xor(mx, 1));
        mx = fmaxf(mx, __shfl_xor(mx, 2));
        float se = __expf(o0 - mx) + __expf(o1 - mx)
                 + __expf(o2 - mx) + __expf(o3 - mx);
        se += __shfl_xor(se, 1);
        se += __shfl_xor(se, 2);
        float ls = mx + logf(se);
        ((float4*)out)[(size_t)node * 4 + pos] =
            make_float4(o0 - ls, o1 - ls, o2 - ls, o3 - ls);
    }
}

// ---------------------------------------------------------------------------

extern "C" void kernel_launch(void* const* d_in, const int* in_sizes, int n_in,
                              void* d_out, int out_size, void* d_ws, size_t ws_size,
                              hipStream_t stream) {
    const float* x    = (const float*)d_in[0];
    const int*   ei   = (const int*)d_in[1];
    const float* W1   = (const float*)d_in[2];
    const float* b1   = (const float*)d_in[3];
    const float* as1  = (const float*)d_in[4];
    const float* ad1  = (const float*)d_in[5];
    const float* W2   = (const float*)d_in[6];
    const float* b2   = (const float*)d_in[7];
    const float* as2  = (const float*)d_in[8];
    const float* ad2  = (const float*)d_in[9];
    float* out = (float*)d_out;

    int N = in_sizes[0] / 128;
    int E = in_sizes[1] / 2;
    const int* srcp = ei;
    const int* dstp = ei + E;
    int nbuck = (N + 511) >> 9;               // 196 for N=100k

    char* w = (char*)d_ws;
    auto alloc = [&](size_t bytes) {
        void* p = (void*)w;
        w += (bytes + 255) & ~(size_t)255;
        return p;
    };
    unsigned short* h1b = (unsigned short*)alloc((size_t)N * 64 * 2);
    float* a_s1  = (float*)alloc((size_t)N * 8 * 4);
    float* a_d1  = (float*)alloc((size_t)N * 8 * 4);
    unsigned short* heb = (unsigned short*)alloc((size_t)N * 64 * 2);
    unsigned short* h2b = (unsigned short*)alloc((size_t)N * 16 * 2);
    float* a_s2b = (float*)alloc((size_t)N * 4);
    float* a_d2b = (float*)alloc((size_t)N * 4);
    int*   rowp  = (int*)alloc((size_t)(N + 1) * 4);
    int*   srcs  = (int*)alloc((size_t)E * 4);
    int*   gcur  = (int*)alloc((size_t)nbuck * 4);
    int*   buf   = (int*)alloc((size_t)nbuck * BCAP * 4);  // 12.85 MB

    hipMemsetAsync(gcur, 0, (size_t)nbuck * 4, stream);

    int bblk = (E + ECHUNK - 1) / ECHUNK;
    bucket_kernel<<<bblk, 1024, 0, stream>>>(srcp, dstp, gcur, buf, E, nbuck);
    csr_bucket_kernel<<<nbuck, 1024, 0, stream>>>(gcur, buf, rowp, srcs, N, E);

    int g1blocks = (N + 63) >> 6;
    gemm1_mfma_kernel<<<g1blocks, 256, 0, stream>>>(x, W1, as1, ad1, h1b, a_s1, a_d1, N);
    agg1_kernel<<<(N + 3) / 4, 256, 0, stream>>>(h1b, a_s1, a_d1, rowp, srcs, b1, heb, 0, N);
    gemm2_kernel<<<2048, 256, 0, stream>>>(heb, W2, as2, ad2, h2b, a_s2b, a_d2b, N);
    agg2_kernel<<<(N + 15) / 16, 256, 0, stream>>>(h2b, a_s2b, a_d2b, rowp, srcs, b2, out, N);
}